// Round 14
// baseline (331.300 us; speedup 1.0000x reference)
//
#include <hip/hip_runtime.h>
#include <hip/hip_bf16.h>

typedef __attribute__((ext_vector_type(4)))  float f32x4;
typedef __attribute__((ext_vector_type(16))) float f32x16;
typedef __attribute__((ext_vector_type(8)))  short s16x8;

#define MFMA(a,b,c)   __builtin_amdgcn_mfma_f32_16x16x32_bf16(a,b,c,0,0,0)
#define MFMA32(a,b,c) __builtin_amdgcn_mfma_f32_32x32x16_bf16(a,b,c,0,0,0)

__device__ __forceinline__ void gll16(const void* gptr, void* lptr){
  auto g = (const __attribute__((address_space(1))) unsigned int*)gptr;
  auto l = (__attribute__((address_space(3))) unsigned int*)lptr;
  __builtin_amdgcn_global_load_lds(g, l, 16, 0, 0);
}

__device__ __forceinline__ void split2(float x, __hip_bfloat16& h, __hip_bfloat16& l){
  h = __float2bfloat16(x);
  l = __float2bfloat16(x - __bfloat162float(h));
}

__device__ __forceinline__ unsigned short bf16bits(float x){
  __hip_bfloat16 h = __float2bfloat16(x);
  return *reinterpret_cast<unsigned short*>(&h);
}
__device__ __forceinline__ unsigned pack2(float lo, float hi){
  return (unsigned)bf16bits(lo) | ((unsigned)bf16bits(hi) << 16);
}
__device__ __forceinline__ void plane32swap(unsigned &a, unsigned &b){
  asm volatile("v_permlane32_swap_b32 %0, %1" : "+v"(a), "+v"(b));
}

// ---------------- fused input split: fp32 -> bf16 (hi; lo only for Wo) ----------------
__global__ __launch_bounds__(256) void split_all(
  const float* __restrict__ Q, const float* __restrict__ K, const float* __restrict__ V,
  const float* __restrict__ Wq, const float* __restrict__ Wk,
  const float* __restrict__ Wv, const float* __restrict__ Wo,
  __hip_bfloat16* __restrict__ QIh,
  __hip_bfloat16* __restrict__ KIh,
  __hip_bfloat16* __restrict__ VIh,
  __hip_bfloat16* __restrict__ Wqh,
  __hip_bfloat16* __restrict__ Wkh,
  __hip_bfloat16* __restrict__ Wvh,
  __hip_bfloat16* __restrict__ Woh, __hip_bfloat16* __restrict__ Wol)
{
  const int NE4 = 786432, WE4 = 147456;
  int i = blockIdx.x*256 + threadIdx.x;
  const float* src; __hip_bfloat16 *dh, *dl = nullptr; int off;
  if (i < 3*NE4){
    int seg = i / NE4; off = i - seg*NE4;
    src = seg==0 ? Q   : (seg==1 ? K   : V);
    dh  = seg==0 ? QIh : (seg==1 ? KIh : VIh);
  } else {
    int j = i - 3*NE4; int seg = j / WE4; off = j - seg*WE4;
    src = seg==0 ? Wq  : (seg==1 ? Wk  : (seg==2 ? Wv  : Wo));
    dh  = seg==0 ? Wqh : (seg==1 ? Wkh : (seg==2 ? Wvh : Woh));
    if (seg == 3) dl = Wol;
  }
  float4 x = ((const float4*)src)[off];
  __hip_bfloat16 h0,l0,h1,l1,h2,l2,h3,l3;
  split2(x.x,h0,l0); split2(x.y,h1,l1); split2(x.z,h2,l2); split2(x.w,h3,l3);
  union { __hip_bfloat16 b[4]; ushort4 u; } H, L;
  H.b[0]=h0; H.b[1]=h1; H.b[2]=h2; H.b[3]=h3;
  L.b[0]=l0; L.b[1]=l1; L.b[2]=l2; L.b[3]=l3;
  *(ushort4*)(dh + (size_t)off*4) = H.u;
  if (dl) *(ushort4*)(dl + (size_t)off*4) = L.u;
}

// ---------------- fused QKV GEMM: uniform 1-term, 2-phase double-buffered ----------------
__global__ __launch_bounds__(256) void gemm_qkv(
    const __hip_bfloat16* __restrict__ QAh,
    const __hip_bfloat16* __restrict__ KAh,
    const __hip_bfloat16* __restrict__ VAh,
    const __hip_bfloat16* __restrict__ WqH,
    const __hip_bfloat16* __restrict__ WkH,
    const __hip_bfloat16* __restrict__ WvH,
    const float* __restrict__ bq, const float* __restrict__ bk, const float* __restrict__ bv,
    float qscale,
    __hip_bfloat16* __restrict__ qhp, __hip_bfloat16* __restrict__ qlp,
    __hip_bfloat16* __restrict__ khp, __hip_bfloat16* __restrict__ vTp)
{
  __shared__ __align__(16) __hip_bfloat16 lds[16384];   // 32 KB: 2 bufs x (A 8KB + B 8KB)

  const int tid = threadIdx.x;
  const int w = tid >> 6, lane = tid & 63, r = lane & 15, g = lane >> 4;
  const int wg = blockIdx.x;
  const int seg = wg / 768;
  const int t = wg % 768;
  const int tm = t / 12, tn = t % 12;

  const __hip_bfloat16* Ah = seg==0 ? QAh : (seg==1 ? KAh : VAh);
  const __hip_bfloat16* Bh = seg==0 ? WqH : (seg==1 ? WkH : WvH);
  const float* bias        = seg==0 ? bq  : (seg==1 ? bk  : bv);

  const char* gA_h = (const char*)Ah + (size_t)tm*64*768*2;
  const char* gB_h = (const char*)Bh + (size_t)tn*64*768*2;

  f32x4 acc[4] = {};

  auto stage = [&](int buf, int kbe){
    #pragma unroll
    for (int i = 0; i < 2; ++i){
      int lb = i*4096 + tid*16;
      int row = lb >> 7, colb = lb & 127;
      gll16(gA_h + (size_t)row*1536 + kbe*2 + colb, (char*)lds + buf*16384 + i*4096 + w*1024);
      gll16(gB_h + (size_t)row*1536 + kbe*2 + colb, (char*)lds + buf*16384 + 8192 + i*4096 + w*1024);
    }
  };
  int cur = 0;
  stage(0, 0);
  __syncthreads();
  for (int it = 0; it < 12; ++it){
    if (it + 1 < 12) stage(cur ^ 1, (it+1)*64);
    const __hip_bfloat16* A = lds + cur*8192;
    const __hip_bfloat16* B = lds + cur*8192 + 4096;
    #pragma unroll
    for (int c = 0; c < 2; ++c){
      int aoff = (w*16 + r)*64 + c*32 + g*8;
      s16x8 a_h = *(const s16x8*)(A + aoff);
      #pragma unroll
      for (int j = 0; j < 4; ++j){
        s16x8 b_h = *(const s16x8*)(B + (j*16 + r)*64 + c*32 + g*8);
        acc[j] = MFMA(a_h, b_h, acc[j]);
      }
    }
    __syncthreads();
    cur ^= 1;
  }

  #pragma unroll
  for (int j = 0; j < 4; ++j){
    #pragma unroll
    for (int e = 0; e < 4; ++e){
      int m = tm*64 + w*16 + g*4 + e;
      int n = tn*64 + j*16 + r;
      float v = acc[j][e] + bias[n];
      int b = m >> 11, s = m & 2047;
      if (seg == 0){
        v *= qscale;
        __hip_bfloat16 h, l; split2(v, h, l);
        size_t idx = ((size_t)(b*12 + (n>>6))*2048 + s)*64 + (n & 63);
        qhp[idx] = h; qlp[idx] = l;
      } else if (seg == 1){
        size_t idx = ((size_t)(b*12 + (n>>6))*2048 + s)*64 + (n & 63);
        khp[idx] = __float2bfloat16(v);
      } else {
        size_t idx = ((size_t)(b*12 + (n>>6))*64 + (n & 63))*2048 + s;
        vTp[idx] = __float2bfloat16(v);
      }
    }
  }
}

// ---------------- out-proj GEMM: attn[4096x768] x Wo[768x768]^T + bo -> fp32 (3-term) ----------------
__global__ __launch_bounds__(256) void gemm_o(
    const __hip_bfloat16* __restrict__ Ah, const __hip_bfloat16* __restrict__ Al,
    const __hip_bfloat16* __restrict__ Bh, const __hip_bfloat16* __restrict__ Bl,
    const float* __restrict__ bias, float* __restrict__ o_f)
{
  __shared__ __align__(16) __hip_bfloat16 sAh[64*64];
  __shared__ __align__(16) __hip_bfloat16 sAl[64*64];
  __shared__ __align__(16) __hip_bfloat16 sBh[64*64];
  __shared__ __align__(16) __hip_bfloat16 sBl[64*64];

  const int tid = threadIdx.x;
  const int w = tid >> 6, lane = tid & 63, r = lane & 15, g = lane >> 4;
  const int t = blockIdx.x;
  const int tm = t / 12, tn = t % 12;

  const char* gA_h = (const char*)Ah + (size_t)tm*64*768*2;
  const char* gA_l = (const char*)Al + (size_t)tm*64*768*2;
  const char* gB_h = (const char*)Bh + (size_t)tn*64*768*2;
  const char* gB_l = (const char*)Bl + (size_t)tn*64*768*2;

  f32x4 acc[4] = {};

  for (int kb = 0; kb < 768; kb += 64){
    __syncthreads();
    #pragma unroll
    for (int i = 0; i < 2; ++i){
      int lb = i*4096 + tid*16;
      int row = lb >> 7, colb = lb & 127;
      gll16(gA_h + (size_t)row*1536 + kb*2 + colb, (char*)sAh + i*4096 + w*1024);
      gll16(gA_l + (size_t)row*1536 + kb*2 + colb, (char*)sAl + i*4096 + w*1024);
      gll16(gB_h + (size_t)row*1536 + kb*2 + colb, (char*)sBh + i*4096 + w*1024);
      gll16(gB_l + (size_t)row*1536 + kb*2 + colb, (char*)sBl + i*4096 + w*1024);
    }
    __syncthreads();
    #pragma unroll
    for (int c = 0; c < 2; ++c){
      int aoff = (w*16 + r)*64 + c*32 + g*8;
      s16x8 a_h = *(const s16x8*)(sAh + aoff);
      s16x8 a_l = *(const s16x8*)(sAl + aoff);
      #pragma unroll
      for (int j = 0; j < 4; ++j){
        int boff = (j*16 + r)*64 + c*32 + g*8;
        s16x8 b_h = *(const s16x8*)(sBh + boff);
        s16x8 b_l = *(const s16x8*)(sBl + boff);
        acc[j] = MFMA(a_h, b_h, acc[j]);
        acc[j] = MFMA(a_l, b_h, acc[j]);
        acc[j] = MFMA(a_h, b_l, acc[j]);
      }
    }
  }

  #pragma unroll
  for (int j = 0; j < 4; ++j){
    #pragma unroll
    for (int e = 0; e < 4; ++e){
      int m = tm*64 + w*16 + g*4 + e;
      int n = tn*64 + j*16 + r;
      o_f[(size_t)m*768 + n] = acc[j][e] + bias[n];
    }
  }
}

// ---------------- attn phase 1: softmax denominators ----------------
// grid = 24 bh * 32 qt2 (64 q-rows/block): each K-fragment feeds TWO q-tiles'
// MFMAs (2x load amortization). 1-term QK, 2-deep K prefetch, setprio on MFMA.
__global__ __launch_bounds__(256,4) void attn_l(
    const __hip_bfloat16* __restrict__ qh,
    const __hip_bfloat16* __restrict__ kh,
    float* __restrict__ rlbuf)
{
  __shared__ float ldsL[2][128];
  const int tid  = threadIdx.x;
  const int w    = tid >> 6;
  const int lane = tid & 63;
  const int col  = lane & 31;
  const int hi   = lane >> 5;
  const int bh = blockIdx.x % 24, qt2 = blockIdx.x / 24;

  const __hip_bfloat16* qr0 = qh + ((size_t)bh*2048 + qt2*64 + col)*64 + hi*8;
  const __hip_bfloat16* qr1 = qr0 + 32*64;
  s16x8 Qh0[4], Qh1[4];
  #pragma unroll
  for (int ks = 0; ks < 4; ++ks){
    Qh0[ks] = *(const s16x8*)(qr0 + ks*16);
    Qh1[ks] = *(const s16x8*)(qr1 + ks*16);
  }

  const __hip_bfloat16* kb = kh + (size_t)bh*2048*64;

  s16x8 kfn[4];
  {
    const __hip_bfloat16* kr = kb + ((size_t)(w*16)*32 + col)*64 + hi*8;
    #pragma unroll
    for (int ks = 0; ks < 4; ++ks) kfn[ks] = *(const s16x8*)(kr + ks*16);
  }

  float pa0=0.f, pa1=0.f, pa2=0.f, pa3=0.f;   // tile0 partial sums
  float pb0=0.f, pb1=0.f, pb2=0.f, pb3=0.f;   // tile1
  for (int c = 0; c < 16; ++c){
    s16x8 kf[4];
    #pragma unroll
    for (int ks = 0; ks < 4; ++ks) kf[ks] = kfn[ks];
    if (c < 15){
      const __hip_bfloat16* kr = kb + ((size_t)(w*16 + c + 1)*32 + col)*64 + hi*8;
      #pragma unroll
      for (int ks = 0; ks < 4; ++ks) kfn[ks] = *(const s16x8*)(kr + ks*16);
    }
    f32x16 s0, s1;
    #pragma unroll
    for (int e = 0; e < 16; ++e){ s0[e] = 0.f; s1[e] = 0.f; }
    __builtin_amdgcn_s_setprio(1);
    #pragma unroll
    for (int ks = 0; ks < 4; ++ks){
      s0 = MFMA32(kf[ks], Qh0[ks], s0);
      s1 = MFMA32(kf[ks], Qh1[ks], s1);
    }
    __builtin_amdgcn_s_setprio(0);
    #pragma unroll
    for (int e = 0; e < 16; e += 4){
      pa0 += exp2f(s0[e+0]); pa1 += exp2f(s0[e+1]);
      pa2 += exp2f(s0[e+2]); pa3 += exp2f(s0[e+3]);
      pb0 += exp2f(s1[e+0]); pb1 += exp2f(s1[e+1]);
      pb2 += exp2f(s1[e+2]); pb3 += exp2f(s1[e+3]);
    }
  }
  float l0 = (pa0+pa1) + (pa2+pa3);
  float l1 = (pb0+pb1) + (pb2+pb3);
  l0 += __shfl_xor(l0, 32);
  l1 += __shfl_xor(l1, 32);
  if (lane < 32){
    ldsL[0][w*32 + col] = l0;
    ldsL[1][w*32 + col] = l1;
  }
  __syncthreads();
  if (tid < 64){
    int tt = tid >> 5, q = tid & 31;
    float lt = (ldsL[tt][q] + ldsL[tt][32+q]) + (ldsL[tt][64+q] + ldsL[tt][96+q]);
    rlbuf[(size_t)bh*2048 + qt2*64 + tt*32 + q] = 1.0f / lt;
  }
}

// ---------------- attn phase 2: weights + PV, single sweep ----------------
// 2-term QK, 2-deep K prefetch, setprio around MFMA clusters, STORE-LATE W path
// (LDS transpose + global store after the PV MFMAs: stores drain under next
// chunk's compute). ldsX aliased as PV merge buffer.
__global__ __launch_bounds__(256,4) void attn_pv(
    const __hip_bfloat16* __restrict__ qh, const __hip_bfloat16* __restrict__ ql,
    const __hip_bfloat16* __restrict__ kh,
    const __hip_bfloat16* __restrict__ vT,
    const float* __restrict__ rlbuf,
    float* __restrict__ wout,
    __hip_bfloat16* __restrict__ attnh, __hip_bfloat16* __restrict__ attnl)
{
  __shared__ __align__(16) float ldsX[4*32*36];   // 18 KB: per-wave W scratch / PV merge
  __shared__ float ldsRL[32];

  const int tid  = threadIdx.x;
  const int w    = tid >> 6;
  const int lane = tid & 63;
  const int col  = lane & 31;
  const int hi   = lane >> 5;
  const int bh = blockIdx.x % 24, qt = blockIdx.x / 24;

  const __hip_bfloat16* qr_h = qh + ((size_t)bh*2048 + qt*32 + col)*64 + hi*8;
  const __hip_bfloat16* qr_l = ql + ((size_t)bh*2048 + qt*32 + col)*64 + hi*8;
  s16x8 Qh[4], Ql[4];
  #pragma unroll
  for (int ks = 0; ks < 4; ++ks){
    Qh[ks] = *(const s16x8*)(qr_h + ks*16);
    Ql[ks] = *(const s16x8*)(qr_l + ks*16);
  }

  if (tid < 32) ldsRL[tid] = rlbuf[(size_t)bh*2048 + qt*32 + tid];
  __syncthreads();
  const float rl = ldsRL[col];

  const __hip_bfloat16* kb = kh + (size_t)bh*2048*64;     // [key][64]
  const __hip_bfloat16* vb = vT + (size_t)bh*64*2048;     // [d][key]
  float* W = ldsX + w*1152;                               // 32 x 36 floats

  s16x8 kfn[4];
  {
    const __hip_bfloat16* kr = kb + ((size_t)(w*16)*32 + col)*64 + hi*8;
    #pragma unroll
    for (int ks = 0; ks < 4; ++ks) kfn[ks] = *(const s16x8*)(kr + ks*16);
  }

  f32x16 pv0, pv1;
  #pragma unroll
  for (int e = 0; e < 16; ++e){ pv0[e]=0.f; pv1[e]=0.f; }
  float* wq = wout + ((size_t)bh*2048 + (size_t)qt*32)*2048;

  for (int c = 0; c < 16; ++c){
    const int key0 = (w*16 + c)*32;
    s16x8 kf[4];
    #pragma unroll
    for (int ks = 0; ks < 4; ++ks) kf[ks] = kfn[ks];
    if (c < 15){
      const __hip_bfloat16* kr = kb + ((size_t)(w*16 + c + 1)*32 + col)*64 + hi*8;
      #pragma unroll
      for (int ks = 0; ks < 4; ++ks) kfn[ks] = *(const s16x8*)(kr + ks*16);
    }
    s16x8 vv[2][2];
    #pragma unroll
    for (int ww = 0; ww < 2; ++ww)
      #pragma unroll
      for (int dt = 0; dt < 2; ++dt)
        vv[ww][dt] = *(const s16x8*)(vb + ((size_t)(dt*32+col)*2048 + key0 + ww*16 + hi*8));

    f32x16 s0;
    #pragma unroll
    for (int e = 0; e < 16; ++e) s0[e] = 0.f;
    __builtin_amdgcn_s_setprio(1);
    #pragma unroll
    for (int ks = 0; ks < 4; ++ks){
      s0 = MFMA32(kf[ks], Qh[ks], s0);
      s0 = MFMA32(kf[ks], Ql[ks], s0);
    }
    __builtin_amdgcn_s_setprio(0);
    #pragma unroll
    for (int e = 0; e < 16; ++e) s0[e] = exp2f(s0[e]);   // unnormalized p, q-row = col

    // ---- pack p -> bf16 A-frags, PV (ahead of the store path) ----
    __builtin_amdgcn_s_setprio(1);
    #pragma unroll
    for (int ww = 0; ww < 2; ++ww){
      const int e0 = ww*8;
      unsigned wa = pack2(s0[e0+0], s0[e0+1]);
      unsigned wb = pack2(s0[e0+2], s0[e0+3]);
      unsigned wc = pack2(s0[e0+4], s0[e0+5]);
      unsigned wd = pack2(s0[e0+6], s0[e0+7]);
      plane32swap(wa, wc);
      plane32swap(wb, wd);
      union { unsigned u[4]; s16x8 v; } cv;
      cv.u[0]=wa; cv.u[1]=wb; cv.u[2]=wc; cv.u[3]=wd;
      pv0 = MFMA32(cv.v, vv[ww][0], pv0);
      pv1 = MFMA32(cv.v, vv[ww][1], pv1);
    }
    __builtin_amdgcn_s_setprio(0);

    // ---- STORE-LATE: normalized weights -> LDS transpose -> coalesced global ----
    #pragma unroll
    for (int rq = 0; rq < 4; ++rq){
      f32x4 f;
      f[0]=s0[rq*4+0]*rl; f[1]=s0[rq*4+1]*rl; f[2]=s0[rq*4+2]*rl; f[3]=s0[rq*4+3]*rl;
      *(f32x4*)(W + col*36 + rq*8 + hi*4) = f;           // key idx rq*8+hi*4+j
    }
    #pragma unroll
    for (int it = 0; it < 4; ++it){
      int q  = it*8 + (lane>>3);
      int k4 = (lane&7)*4;
      f32x4 f = *(const f32x4*)(W + q*36 + k4);
      *(f32x4*)(wq + (size_t)q*2048 + key0 + k4) = f;    // 8 rows x 128B per instr
    }
  }

  __syncthreads();   // ldsX transitions from W-scratch to PV-merge buffer

  float* ldsPV = ldsX;
  if (w >= 2){
    const int buf = w - 2;
    #pragma unroll
    for (int e = 0; e < 16; ++e){
      ldsPV[(e)   *128 + buf*64 + lane] = pv0[e];
      ldsPV[(16+e)*128 + buf*64 + lane] = pv1[e];
    }
  }
  __syncthreads();
  if (w < 2){
    #pragma unroll
    for (int e = 0; e < 16; ++e){
      pv0[e] += ldsPV[(e)   *128 + w*64 + lane];
      pv1[e] += ldsPV[(16+e)*128 + w*64 + lane];
    }
  }
  __syncthreads();
  if (w == 1){
    #pragma unroll
    for (int e = 0; e < 16; ++e){
      ldsPV[(e)   *128 + lane] = pv0[e];
      ldsPV[(16+e)*128 + lane] = pv1[e];
    }
  }
  __syncthreads();
  if (w == 0){
    #pragma unroll
    for (int e = 0; e < 16; ++e){
      pv0[e] += ldsPV[(e)   *128 + lane];
      pv1[e] += ldsPV[(16+e)*128 + lane];
    }
    const int b_ = bh / 12, hh = bh % 12;
    #pragma unroll
    for (int e = 0; e < 16; ++e){
      int qsub = (e&3) + 8*(e>>2) + 4*hi;        // q-row of THIS register (PV D-layout)
      float re = ldsRL[qsub];
      int qrow = qt*32 + qsub;
      size_t base = ((size_t)b_*2048 + qrow)*768 + hh*64;
      __hip_bfloat16 h0, l0, h1, l1;
      split2(pv0[e]*re, h0, l0);
      split2(pv1[e]*re, h1, l1);
      attnh[base + col]      = h0; attnl[base + col]      = l0;
      attnh[base + 32 + col] = h1; attnl[base + 32 + col] = l1;
    }
  }
}

// ---------------- launch ----------------
extern "C" void kernel_launch(void* const* d_in, const int* in_sizes, int n_in,
                              void* d_out, int out_size, void* d_ws, size_t ws_size,
                              hipStream_t stream){
  const float* Q  = (const float*)d_in[0];
  const float* Kx = (const float*)d_in[1];
  const float* V  = (const float*)d_in[2];
  const float* Wq = (const float*)d_in[3];
  const float* bq = (const float*)d_in[4];
  const float* Wk = (const float*)d_in[5];
  const float* bk = (const float*)d_in[6];
  const float* Wv = (const float*)d_in[7];
  const float* bv = (const float*)d_in[8];
  const float* Wo = (const float*)d_in[9];
  const float* bo = (const float*)d_in[10];

  float* out = (float*)d_out;
  float* wts = out + (size_t)2*2048*768;

  char* cur = (char*)d_ws;
  auto alloc = [&](size_t elems)->__hip_bfloat16*{
    __hip_bfloat16* p = (__hip_bfloat16*)cur;
    cur += ((elems*2 + 255) & ~(size_t)255);
    return p;
  };
  const size_t NE = (size_t)4096*768;
  const size_t WE = (size_t)768*768;

  __hip_bfloat16 *QIh=alloc(NE), *KIh=alloc(NE), *VIh=alloc(NE);
  __hip_bfloat16 *Wqh=alloc(WE), *Wkh=alloc(WE), *Wvh=alloc(WE),
                 *Woh=alloc(WE), *Wol=alloc(WE);
  __hip_bfloat16 *qhp=alloc(NE), *qlp=alloc(NE), *khp=alloc(NE),
                 *vTp=alloc(NE);
  __hip_bfloat16 *ath=alloc(NE), *atl=alloc(NE);
  float* rlbuf = (float*)alloc(2*24*2048);   // 49152 floats

  split_all<<<11520, 256, 0, stream>>>(Q, Kx, V, Wq, Wk, Wv, Wo,
      QIh, KIh, VIh, Wqh, Wkh, Wvh, Woh, Wol);

  // log2-domain softmax: bake log2(e)/8 into the Q projection scale
  gemm_qkv<<<2304, 256, 0, stream>>>(
      QIh, KIh, VIh,
      Wqh, Wkh, Wvh,
      bq, bk, bv, 0.18033688011112042f,
      qhp, qlp, khp, vTp);

  attn_l <<<768,  256, 0, stream>>>(qhp, khp, rlbuf);
  attn_pv<<<1536, 256, 0, stream>>>(qhp, qlp, khp, vTp, rlbuf, wts, ath, atl);

  gemm_o<<<768, 256, 0, stream>>>(ath,atl,Woh,Wol,bo, out);
}

// Round 15
// 287.318 us; speedup vs baseline: 1.1531x; 1.1531x over previous
//
#include <hip/hip_runtime.h>
#include <hip/hip_bf16.h>

typedef __attribute__((ext_vector_type(4)))  float f32x4;
typedef __attribute__((ext_vector_type(16))) float f32x16;
typedef __attribute__((ext_vector_type(8)))  short s16x8;

#define MFMA(a,b,c)   __builtin_amdgcn_mfma_f32_16x16x32_bf16(a,b,c,0,0,0)
#define MFMA32(a,b,c) __builtin_amdgcn_mfma_f32_32x32x16_bf16(a,b,c,0,0,0)

__device__ __forceinline__ void gll16(const void* gptr, void* lptr){
  auto g = (const __attribute__((address_space(1))) unsigned int*)gptr;
  auto l = (__attribute__((address_space(3))) unsigned int*)lptr;
  __builtin_amdgcn_global_load_lds(g, l, 16, 0, 0);
}

__device__ __forceinline__ void split2(float x, __hip_bfloat16& h, __hip_bfloat16& l){
  h = __float2bfloat16(x);
  l = __float2bfloat16(x - __bfloat162float(h));
}

__device__ __forceinline__ unsigned short bf16bits(float x){
  __hip_bfloat16 h = __float2bfloat16(x);
  return *reinterpret_cast<unsigned short*>(&h);
}
__device__ __forceinline__ unsigned pack2(float lo, float hi){
  return (unsigned)bf16bits(lo) | ((unsigned)bf16bits(hi) << 16);
}
__device__ __forceinline__ void plane32swap(unsigned &a, unsigned &b){
  asm volatile("v_permlane32_swap_b32 %0, %1" : "+v"(a), "+v"(b));
}

// ---------------- fused input split: fp32 -> bf16 (hi; lo only for Wo) ----------------
__global__ __launch_bounds__(256) void split_all(
  const float* __restrict__ Q, const float* __restrict__ K, const float* __restrict__ V,
  const float* __restrict__ Wq, const float* __restrict__ Wk,
  const float* __restrict__ Wv, const float* __restrict__ Wo,
  __hip_bfloat16* __restrict__ QIh,
  __hip_bfloat16* __restrict__ KIh,
  __hip_bfloat16* __restrict__ VIh,
  __hip_bfloat16* __restrict__ Wqh,
  __hip_bfloat16* __restrict__ Wkh,
  __hip_bfloat16* __restrict__ Wvh,
  __hip_bfloat16* __restrict__ Woh, __hip_bfloat16* __restrict__ Wol)
{
  const int NE4 = 786432, WE4 = 147456;
  int i = blockIdx.x*256 + threadIdx.x;
  const float* src; __hip_bfloat16 *dh, *dl = nullptr; int off;
  if (i < 3*NE4){
    int seg = i / NE4; off = i - seg*NE4;
    src = seg==0 ? Q   : (seg==1 ? K   : V);
    dh  = seg==0 ? QIh : (seg==1 ? KIh : VIh);
  } else {
    int j = i - 3*NE4; int seg = j / WE4; off = j - seg*WE4;
    src = seg==0 ? Wq  : (seg==1 ? Wk  : (seg==2 ? Wv  : Wo));
    dh  = seg==0 ? Wqh : (seg==1 ? Wkh : (seg==2 ? Wvh : Woh));
    if (seg == 3) dl = Wol;
  }
  float4 x = ((const float4*)src)[off];
  __hip_bfloat16 h0,l0,h1,l1,h2,l2,h3,l3;
  split2(x.x,h0,l0); split2(x.y,h1,l1); split2(x.z,h2,l2); split2(x.w,h3,l3);
  union { __hip_bfloat16 b[4]; ushort4 u; } H, L;
  H.b[0]=h0; H.b[1]=h1; H.b[2]=h2; H.b[3]=h3;
  L.b[0]=l0; L.b[1]=l1; L.b[2]=l2; L.b[3]=l3;
  *(ushort4*)(dh + (size_t)off*4) = H.u;
  if (dl) *(ushort4*)(dl + (size_t)off*4) = L.u;
}

// ---------------- fused QKV GEMM: uniform 1-term, 2-phase double-buffered ----------------
__global__ __launch_bounds__(256) void gemm_qkv(
    const __hip_bfloat16* __restrict__ QAh,
    const __hip_bfloat16* __restrict__ KAh,
    const __hip_bfloat16* __restrict__ VAh,
    const __hip_bfloat16* __restrict__ WqH,
    const __hip_bfloat16* __restrict__ WkH,
    const __hip_bfloat16* __restrict__ WvH,
    const float* __restrict__ bq, const float* __restrict__ bk, const float* __restrict__ bv,
    float qscale,
    __hip_bfloat16* __restrict__ qhp, __hip_bfloat16* __restrict__ qlp,
    __hip_bfloat16* __restrict__ khp, __hip_bfloat16* __restrict__ vTp)
{
  __shared__ __align__(16) __hip_bfloat16 lds[16384];   // 32 KB: 2 bufs x (A 8KB + B 8KB)

  const int tid = threadIdx.x;
  const int w = tid >> 6, lane = tid & 63, r = lane & 15, g = lane >> 4;
  const int wg = blockIdx.x;
  const int seg = wg / 768;
  const int t = wg % 768;
  const int tm = t / 12, tn = t % 12;

  const __hip_bfloat16* Ah = seg==0 ? QAh : (seg==1 ? KAh : VAh);
  const __hip_bfloat16* Bh = seg==0 ? WqH : (seg==1 ? WkH : WvH);
  const float* bias        = seg==0 ? bq  : (seg==1 ? bk  : bv);

  const char* gA_h = (const char*)Ah + (size_t)tm*64*768*2;
  const char* gB_h = (const char*)Bh + (size_t)tn*64*768*2;

  f32x4 acc[4] = {};

  auto stage = [&](int buf, int kbe){
    #pragma unroll
    for (int i = 0; i < 2; ++i){
      int lb = i*4096 + tid*16;
      int row = lb >> 7, colb = lb & 127;
      gll16(gA_h + (size_t)row*1536 + kbe*2 + colb, (char*)lds + buf*16384 + i*4096 + w*1024);
      gll16(gB_h + (size_t)row*1536 + kbe*2 + colb, (char*)lds + buf*16384 + 8192 + i*4096 + w*1024);
    }
  };
  int cur = 0;
  stage(0, 0);
  __syncthreads();
  for (int it = 0; it < 12; ++it){
    if (it + 1 < 12) stage(cur ^ 1, (it+1)*64);
    const __hip_bfloat16* A = lds + cur*8192;
    const __hip_bfloat16* B = lds + cur*8192 + 4096;
    #pragma unroll
    for (int c = 0; c < 2; ++c){
      int aoff = (w*16 + r)*64 + c*32 + g*8;
      s16x8 a_h = *(const s16x8*)(A + aoff);
      #pragma unroll
      for (int j = 0; j < 4; ++j){
        s16x8 b_h = *(const s16x8*)(B + (j*16 + r)*64 + c*32 + g*8);
        acc[j] = MFMA(a_h, b_h, acc[j]);
      }
    }
    __syncthreads();
    cur ^= 1;
  }

  #pragma unroll
  for (int j = 0; j < 4; ++j){
    #pragma unroll
    for (int e = 0; e < 4; ++e){
      int m = tm*64 + w*16 + g*4 + e;
      int n = tn*64 + j*16 + r;
      float v = acc[j][e] + bias[n];
      int b = m >> 11, s = m & 2047;
      if (seg == 0){
        v *= qscale;
        __hip_bfloat16 h, l; split2(v, h, l);
        size_t idx = ((size_t)(b*12 + (n>>6))*2048 + s)*64 + (n & 63);
        qhp[idx] = h; qlp[idx] = l;
      } else if (seg == 1){
        size_t idx = ((size_t)(b*12 + (n>>6))*2048 + s)*64 + (n & 63);
        khp[idx] = __float2bfloat16(v);
      } else {
        size_t idx = ((size_t)(b*12 + (n>>6))*64 + (n & 63))*2048 + s;
        vTp[idx] = __float2bfloat16(v);
      }
    }
  }
}

// ---------------- out-proj GEMM: attn[4096x768] x Wo[768x768]^T + bo -> fp32 (3-term) ----------------
__global__ __launch_bounds__(256) void gemm_o(
    const __hip_bfloat16* __restrict__ Ah, const __hip_bfloat16* __restrict__ Al,
    const __hip_bfloat16* __restrict__ Bh, const __hip_bfloat16* __restrict__ Bl,
    const float* __restrict__ bias, float* __restrict__ o_f)
{
  __shared__ __align__(16) __hip_bfloat16 sAh[64*64];
  __shared__ __align__(16) __hip_bfloat16 sAl[64*64];
  __shared__ __align__(16) __hip_bfloat16 sBh[64*64];
  __shared__ __align__(16) __hip_bfloat16 sBl[64*64];

  const int tid = threadIdx.x;
  const int w = tid >> 6, lane = tid & 63, r = lane & 15, g = lane >> 4;
  const int t = blockIdx.x;
  const int tm = t / 12, tn = t % 12;

  const char* gA_h = (const char*)Ah + (size_t)tm*64*768*2;
  const char* gA_l = (const char*)Al + (size_t)tm*64*768*2;
  const char* gB_h = (const char*)Bh + (size_t)tn*64*768*2;
  const char* gB_l = (const char*)Bl + (size_t)tn*64*768*2;

  f32x4 acc[4] = {};

  for (int kb = 0; kb < 768; kb += 64){
    __syncthreads();
    #pragma unroll
    for (int i = 0; i < 2; ++i){
      int lb = i*4096 + tid*16;
      int row = lb >> 7, colb = lb & 127;
      gll16(gA_h + (size_t)row*1536 + kb*2 + colb, (char*)sAh + i*4096 + w*1024);
      gll16(gA_l + (size_t)row*1536 + kb*2 + colb, (char*)sAl + i*4096 + w*1024);
      gll16(gB_h + (size_t)row*1536 + kb*2 + colb, (char*)sBh + i*4096 + w*1024);
      gll16(gB_l + (size_t)row*1536 + kb*2 + colb, (char*)sBl + i*4096 + w*1024);
    }
    __syncthreads();
    #pragma unroll
    for (int c = 0; c < 2; ++c){
      int aoff = (w*16 + r)*64 + c*32 + g*8;
      s16x8 a_h = *(const s16x8*)(sAh + aoff);
      s16x8 a_l = *(const s16x8*)(sAl + aoff);
      #pragma unroll
      for (int j = 0; j < 4; ++j){
        int boff = (j*16 + r)*64 + c*32 + g*8;
        s16x8 b_h = *(const s16x8*)(sBh + boff);
        s16x8 b_l = *(const s16x8*)(sBl + boff);
        acc[j] = MFMA(a_h, b_h, acc[j]);
        acc[j] = MFMA(a_l, b_h, acc[j]);
        acc[j] = MFMA(a_h, b_l, acc[j]);
      }
    }
  }

  #pragma unroll
  for (int j = 0; j < 4; ++j){
    #pragma unroll
    for (int e = 0; e < 4; ++e){
      int m = tm*64 + w*16 + g*4 + e;
      int n = tn*64 + j*16 + r;
      o_f[(size_t)m*768 + n] = acc[j][e] + bias[n];
    }
  }
}

// ---------------- attn phase 1: softmax denominators (R13 version, reverted) ----------------
// grid = 24 bh * 64 qt. 1-term QK, 2-deep K-register prefetch.
__global__ __launch_bounds__(256,4) void attn_l(
    const __hip_bfloat16* __restrict__ qh,
    const __hip_bfloat16* __restrict__ kh,
    float* __restrict__ rlbuf)
{
  __shared__ float ldsL[128];
  const int tid  = threadIdx.x;
  const int w    = tid >> 6;
  const int lane = tid & 63;
  const int col  = lane & 31;
  const int hi   = lane >> 5;
  const int bh = blockIdx.x % 24, qt = blockIdx.x / 24;

  const __hip_bfloat16* qr_h = qh + ((size_t)bh*2048 + qt*32 + col)*64 + hi*8;
  s16x8 Qh[4];
  #pragma unroll
  for (int ks = 0; ks < 4; ++ks) Qh[ks] = *(const s16x8*)(qr_h + ks*16);

  const __hip_bfloat16* kb = kh + (size_t)bh*2048*64;

  s16x8 kfn[4];
  {
    const __hip_bfloat16* kr = kb + ((size_t)(w*16)*32 + col)*64 + hi*8;
    #pragma unroll
    for (int ks = 0; ks < 4; ++ks) kfn[ks] = *(const s16x8*)(kr + ks*16);
  }

  float ps0=0.f, ps1=0.f, ps2=0.f, ps3=0.f;
  for (int c = 0; c < 16; ++c){
    s16x8 kf[4];
    #pragma unroll
    for (int ks = 0; ks < 4; ++ks) kf[ks] = kfn[ks];
    if (c < 15){
      const __hip_bfloat16* kr = kb + ((size_t)(w*16 + c + 1)*32 + col)*64 + hi*8;
      #pragma unroll
      for (int ks = 0; ks < 4; ++ks) kfn[ks] = *(const s16x8*)(kr + ks*16);
    }
    f32x16 s0;
    #pragma unroll
    for (int e = 0; e < 16; ++e) s0[e] = 0.f;
    #pragma unroll
    for (int ks = 0; ks < 4; ++ks) s0 = MFMA32(kf[ks], Qh[ks], s0);
    #pragma unroll
    for (int e = 0; e < 16; e += 4){
      ps0 += exp2f(s0[e+0]); ps1 += exp2f(s0[e+1]);
      ps2 += exp2f(s0[e+2]); ps3 += exp2f(s0[e+3]);
    }
  }
  float l_w = (ps0+ps1) + (ps2+ps3);
  l_w += __shfl_xor(l_w, 32);
  if (lane < 32) ldsL[w*32 + col] = l_w;
  __syncthreads();
  if (tid < 32){
    float lt = (ldsL[tid] + ldsL[32+tid]) + (ldsL[64+tid] + ldsL[96+tid]);
    rlbuf[(size_t)bh*2048 + qt*32 + tid] = 1.0f / lt;
  }
}

// ---------------- attn phase 2: weights + PV (R13 + STORE-LATE only; no setprio) ----------------
// 2-term QK, 2-deep K prefetch. The W LDS-transpose + global store moved AFTER the
// PV MFMAs (stores drain under next chunk's prefetched-K compute). Single delta vs R13.
__global__ __launch_bounds__(256,4) void attn_pv(
    const __hip_bfloat16* __restrict__ qh, const __hip_bfloat16* __restrict__ ql,
    const __hip_bfloat16* __restrict__ kh,
    const __hip_bfloat16* __restrict__ vT,
    const float* __restrict__ rlbuf,
    float* __restrict__ wout,
    __hip_bfloat16* __restrict__ attnh, __hip_bfloat16* __restrict__ attnl)
{
  __shared__ __align__(16) float ldsX[4*32*36];   // 18 KB: per-wave W scratch / PV merge
  __shared__ float ldsRL[32];

  const int tid  = threadIdx.x;
  const int w    = tid >> 6;
  const int lane = tid & 63;
  const int col  = lane & 31;
  const int hi   = lane >> 5;
  const int bh = blockIdx.x % 24, qt = blockIdx.x / 24;

  const __hip_bfloat16* qr_h = qh + ((size_t)bh*2048 + qt*32 + col)*64 + hi*8;
  const __hip_bfloat16* qr_l = ql + ((size_t)bh*2048 + qt*32 + col)*64 + hi*8;
  s16x8 Qh[4], Ql[4];
  #pragma unroll
  for (int ks = 0; ks < 4; ++ks){
    Qh[ks] = *(const s16x8*)(qr_h + ks*16);
    Ql[ks] = *(const s16x8*)(qr_l + ks*16);
  }

  if (tid < 32) ldsRL[tid] = rlbuf[(size_t)bh*2048 + qt*32 + tid];
  __syncthreads();
  const float rl = ldsRL[col];

  const __hip_bfloat16* kb = kh + (size_t)bh*2048*64;     // [key][64]
  const __hip_bfloat16* vb = vT + (size_t)bh*64*2048;     // [d][key]
  float* W = ldsX + w*1152;                               // 32 x 36 floats

  s16x8 kfn[4];
  {
    const __hip_bfloat16* kr = kb + ((size_t)(w*16)*32 + col)*64 + hi*8;
    #pragma unroll
    for (int ks = 0; ks < 4; ++ks) kfn[ks] = *(const s16x8*)(kr + ks*16);
  }

  f32x16 pv0, pv1;
  #pragma unroll
  for (int e = 0; e < 16; ++e){ pv0[e]=0.f; pv1[e]=0.f; }
  float* wq = wout + ((size_t)bh*2048 + (size_t)qt*32)*2048;

  for (int c = 0; c < 16; ++c){
    const int key0 = (w*16 + c)*32;
    s16x8 kf[4];
    #pragma unroll
    for (int ks = 0; ks < 4; ++ks) kf[ks] = kfn[ks];
    if (c < 15){
      const __hip_bfloat16* kr = kb + ((size_t)(w*16 + c + 1)*32 + col)*64 + hi*8;
      #pragma unroll
      for (int ks = 0; ks < 4; ++ks) kfn[ks] = *(const s16x8*)(kr + ks*16);
    }
    s16x8 vv[2][2];
    #pragma unroll
    for (int ww = 0; ww < 2; ++ww)
      #pragma unroll
      for (int dt = 0; dt < 2; ++dt)
        vv[ww][dt] = *(const s16x8*)(vb + ((size_t)(dt*32+col)*2048 + key0 + ww*16 + hi*8));

    f32x16 s0;
    #pragma unroll
    for (int e = 0; e < 16; ++e) s0[e] = 0.f;
    #pragma unroll
    for (int ks = 0; ks < 4; ++ks){
      s0 = MFMA32(kf[ks], Qh[ks], s0);
      s0 = MFMA32(kf[ks], Ql[ks], s0);
    }
    #pragma unroll
    for (int e = 0; e < 16; ++e) s0[e] = exp2f(s0[e]);   // unnormalized p, q-row = col

    // ---- pack p -> bf16 A-frags, PV (ahead of the store path) ----
    #pragma unroll
    for (int ww = 0; ww < 2; ++ww){
      const int e0 = ww*8;
      unsigned wa = pack2(s0[e0+0], s0[e0+1]);
      unsigned wb = pack2(s0[e0+2], s0[e0+3]);
      unsigned wc = pack2(s0[e0+4], s0[e0+5]);
      unsigned wd = pack2(s0[e0+6], s0[e0+7]);
      plane32swap(wa, wc);
      plane32swap(wb, wd);
      union { unsigned u[4]; s16x8 v; } cv;
      cv.u[0]=wa; cv.u[1]=wb; cv.u[2]=wc; cv.u[3]=wd;
      pv0 = MFMA32(cv.v, vv[ww][0], pv0);
      pv1 = MFMA32(cv.v, vv[ww][1], pv1);
    }

    // ---- STORE-LATE: normalized weights -> LDS transpose -> coalesced global ----
    #pragma unroll
    for (int rq = 0; rq < 4; ++rq){
      f32x4 f;
      f[0]=s0[rq*4+0]*rl; f[1]=s0[rq*4+1]*rl; f[2]=s0[rq*4+2]*rl; f[3]=s0[rq*4+3]*rl;
      *(f32x4*)(W + col*36 + rq*8 + hi*4) = f;           // key idx rq*8+hi*4+j
    }
    #pragma unroll
    for (int it = 0; it < 4; ++it){
      int q  = it*8 + (lane>>3);
      int k4 = (lane&7)*4;
      f32x4 f = *(const f32x4*)(W + q*36 + k4);
      *(f32x4*)(wq + (size_t)q*2048 + key0 + k4) = f;    // 8 rows x 128B per instr
    }
  }

  __syncthreads();   // ldsX transitions from W-scratch to PV-merge buffer

  float* ldsPV = ldsX;
  if (w >= 2){
    const int buf = w - 2;
    #pragma unroll
    for (int e = 0; e < 16; ++e){
      ldsPV[(e)   *128 + buf*64 + lane] = pv0[e];
      ldsPV[(16+e)*128 + buf*64 + lane] = pv1[e];
    }
  }
  __syncthreads();
  if (w < 2){
    #pragma unroll
    for (int e = 0; e < 16; ++e){
      pv0[e] += ldsPV[(e)   *128 + w*64 + lane];
      pv1[e] += ldsPV[(16+e)*128 + w*64 + lane];
    }
  }
  __syncthreads();
  if (w == 1){
    #pragma unroll
    for (int e = 0; e < 16; ++e){
      ldsPV[(e)   *128 + lane] = pv0[e];
      ldsPV[(16+e)*128 + lane] = pv1[e];
    }
  }
  __syncthreads();
  if (w == 0){
    #pragma unroll
    for (int e = 0; e < 16; ++e){
      pv0[e] += ldsPV[(e)   *128 + lane];
      pv1[e] += ldsPV[(16+e)*128 + lane];
    }
    const int b_ = bh / 12, hh = bh % 12;
    #pragma unroll
    for (int e = 0; e < 16; ++e){
      int qsub = (e&3) + 8*(e>>2) + 4*hi;        // q-row of THIS register (PV D-layout)
      float re = ldsRL[qsub];
      int qrow = qt*32 + qsub;
      size_t base = ((size_t)b_*2048 + qrow)*768 + hh*64;
      __hip_bfloat16 h0, l0, h1, l1;
      split2(pv0[e]*re, h0, l0);
      split2(pv1[e]*re, h1, l1);
      attnh[base + col]      = h0; attnl[base + col]      = l0;
      attnh[base + 32 + col] = h1; attnl[base + 32 + col] = l1;
    }
  }
}

// ---------------- launch ----------------
extern "C" void kernel_launch(void* const* d_in, const int* in_sizes, int n_in,
                              void* d_out, int out_size, void* d_ws, size_t ws_size,
                              hipStream_t stream){
  const float* Q  = (const float*)d_in[0];
  const float* Kx = (const float*)d_in[1];
  const float* V  = (const float*)d_in[2];
  const float* Wq = (const float*)d_in[3];
  const float* bq = (const float*)d_in[4];
  const float* Wk = (const float*)d_in[5];
  const float* bk = (const float*)d_in[6];
  const float* Wv = (const float*)d_in[7];
  const float* bv = (const float*)d_in[8];
  const float* Wo = (const float*)d_in[9];
  const float* bo = (const float*)d_in[10];

  float* out = (float*)d_out;
  float* wts = out + (size_t)2*2048*768;

  char* cur = (char*)d_ws;
  auto alloc = [&](size_t elems)->__hip_bfloat16*{
    __hip_bfloat16* p = (__hip_bfloat16*)cur;
    cur += ((elems*2 + 255) & ~(size_t)255);
    return p;
  };
  const size_t NE = (size_t)4096*768;
  const size_t WE = (size_t)768*768;

  __hip_bfloat16 *QIh=alloc(NE), *KIh=alloc(NE), *VIh=alloc(NE);
  __hip_bfloat16 *Wqh=alloc(WE), *Wkh=alloc(WE), *Wvh=alloc(WE),
                 *Woh=alloc(WE), *Wol=alloc(WE);
  __hip_bfloat16 *qhp=alloc(NE), *qlp=alloc(NE), *khp=alloc(NE),
                 *vTp=alloc(NE);
  __hip_bfloat16 *ath=alloc(NE), *atl=alloc(NE);
  float* rlbuf = (float*)alloc(2*24*2048);   // 49152 floats

  split_all<<<11520, 256, 0, stream>>>(Q, Kx, V, Wq, Wk, Wv, Wo,
      QIh, KIh, VIh, Wqh, Wkh, Wvh, Woh, Wol);

  // log2-domain softmax: bake log2(e)/8 into the Q projection scale
  gemm_qkv<<<2304, 256, 0, stream>>>(
      QIh, KIh, VIh,
      Wqh, Wkh, Wvh,
      bq, bk, bv, 0.18033688011112042f,
      qhp, qlp, khp, vTp);

  attn_l <<<1536, 256, 0, stream>>>(qhp, khp, rlbuf);
  attn_pv<<<1536, 256, 0, stream>>>(qhp, qlp, khp, vTp, rlbuf, wts, ath, atl);

  gemm_o<<<768, 256, 0, stream>>>(ath,atl,Woh,Wol,bo, out);
}

// Round 16
// 255.696 us; speedup vs baseline: 1.2957x; 1.1237x over previous
//
#include <hip/hip_runtime.h>
#include <hip/hip_bf16.h>

typedef __attribute__((ext_vector_type(4)))  float f32x4;
typedef __attribute__((ext_vector_type(16))) float f32x16;
typedef __attribute__((ext_vector_type(8)))  short s16x8;

#define MFMA(a,b,c)   __builtin_amdgcn_mfma_f32_16x16x32_bf16(a,b,c,0,0,0)
#define MFMA32(a,b,c) __builtin_amdgcn_mfma_f32_32x32x16_bf16(a,b,c,0,0,0)

__device__ __forceinline__ void gll16(const void* gptr, void* lptr){
  auto g = (const __attribute__((address_space(1))) unsigned int*)gptr;
  auto l = (__attribute__((address_space(3))) unsigned int*)lptr;
  __builtin_amdgcn_global_load_lds(g, l, 16, 0, 0);
}

__device__ __forceinline__ void split2(float x, __hip_bfloat16& h, __hip_bfloat16& l){
  h = __float2bfloat16(x);
  l = __float2bfloat16(x - __bfloat162float(h));
}

__device__ __forceinline__ unsigned short bf16bits(float x){
  __hip_bfloat16 h = __float2bfloat16(x);
  return *reinterpret_cast<unsigned short*>(&h);
}
__device__ __forceinline__ unsigned pack2(float lo, float hi){
  return (unsigned)bf16bits(lo) | ((unsigned)bf16bits(hi) << 16);
}
__device__ __forceinline__ void plane32swap(unsigned &a, unsigned &b){
  asm volatile("v_permlane32_swap_b32 %0, %1" : "+v"(a), "+v"(b));
}

// ---------------- fused input split: fp32 -> bf16 (hi; lo only for Wo) ----------------
__global__ __launch_bounds__(256) void split_all(
  const float* __restrict__ Q, const float* __restrict__ K, const float* __restrict__ V,
  const float* __restrict__ Wq, const float* __restrict__ Wk,
  const float* __restrict__ Wv, const float* __restrict__ Wo,
  __hip_bfloat16* __restrict__ QIh,
  __hip_bfloat16* __restrict__ KIh,
  __hip_bfloat16* __restrict__ VIh,
  __hip_bfloat16* __restrict__ Wqh,
  __hip_bfloat16* __restrict__ Wkh,
  __hip_bfloat16* __restrict__ Wvh,
  __hip_bfloat16* __restrict__ Woh, __hip_bfloat16* __restrict__ Wol)
{
  const int NE4 = 786432, WE4 = 147456;
  int i = blockIdx.x*256 + threadIdx.x;
  const float* src; __hip_bfloat16 *dh, *dl = nullptr; int off;
  if (i < 3*NE4){
    int seg = i / NE4; off = i - seg*NE4;
    src = seg==0 ? Q   : (seg==1 ? K   : V);
    dh  = seg==0 ? QIh : (seg==1 ? KIh : VIh);
  } else {
    int j = i - 3*NE4; int seg = j / WE4; off = j - seg*WE4;
    src = seg==0 ? Wq  : (seg==1 ? Wk  : (seg==2 ? Wv  : Wo));
    dh  = seg==0 ? Wqh : (seg==1 ? Wkh : (seg==2 ? Wvh : Woh));
    if (seg == 3) dl = Wol;
  }
  float4 x = ((const float4*)src)[off];
  __hip_bfloat16 h0,l0,h1,l1,h2,l2,h3,l3;
  split2(x.x,h0,l0); split2(x.y,h1,l1); split2(x.z,h2,l2); split2(x.w,h3,l3);
  union { __hip_bfloat16 b[4]; ushort4 u; } H, L;
  H.b[0]=h0; H.b[1]=h1; H.b[2]=h2; H.b[3]=h3;
  L.b[0]=l0; L.b[1]=l1; L.b[2]=l2; L.b[3]=l3;
  *(ushort4*)(dh + (size_t)off*4) = H.u;
  if (dl) *(ushort4*)(dl + (size_t)off*4) = L.u;
}

// ---------------- fused QKV GEMM: uniform 1-term, 2-phase double-buffered ----------------
__global__ __launch_bounds__(256) void gemm_qkv(
    const __hip_bfloat16* __restrict__ QAh,
    const __hip_bfloat16* __restrict__ KAh,
    const __hip_bfloat16* __restrict__ VAh,
    const __hip_bfloat16* __restrict__ WqH,
    const __hip_bfloat16* __restrict__ WkH,
    const __hip_bfloat16* __restrict__ WvH,
    const float* __restrict__ bq, const float* __restrict__ bk, const float* __restrict__ bv,
    float qscale,
    __hip_bfloat16* __restrict__ qhp, __hip_bfloat16* __restrict__ qlp,
    __hip_bfloat16* __restrict__ khp, __hip_bfloat16* __restrict__ vTp)
{
  __shared__ __align__(16) __hip_bfloat16 lds[16384];   // 32 KB: 2 bufs x (A 8KB + B 8KB)

  const int tid = threadIdx.x;
  const int w = tid >> 6, lane = tid & 63, r = lane & 15, g = lane >> 4;
  const int wg = blockIdx.x;
  const int seg = wg / 768;
  const int t = wg % 768;
  const int tm = t / 12, tn = t % 12;

  const __hip_bfloat16* Ah = seg==0 ? QAh : (seg==1 ? KAh : VAh);
  const __hip_bfloat16* Bh = seg==0 ? WqH : (seg==1 ? WkH : WvH);
  const float* bias        = seg==0 ? bq  : (seg==1 ? bk  : bv);

  const char* gA_h = (const char*)Ah + (size_t)tm*64*768*2;
  const char* gB_h = (const char*)Bh + (size_t)tn*64*768*2;

  f32x4 acc[4] = {};

  auto stage = [&](int buf, int kbe){
    #pragma unroll
    for (int i = 0; i < 2; ++i){
      int lb = i*4096 + tid*16;
      int row = lb >> 7, colb = lb & 127;
      gll16(gA_h + (size_t)row*1536 + kbe*2 + colb, (char*)lds + buf*16384 + i*4096 + w*1024);
      gll16(gB_h + (size_t)row*1536 + kbe*2 + colb, (char*)lds + buf*16384 + 8192 + i*4096 + w*1024);
    }
  };
  int cur = 0;
  stage(0, 0);
  __syncthreads();
  for (int it = 0; it < 12; ++it){
    if (it + 1 < 12) stage(cur ^ 1, (it+1)*64);
    const __hip_bfloat16* A = lds + cur*8192;
    const __hip_bfloat16* B = lds + cur*8192 + 4096;
    #pragma unroll
    for (int c = 0; c < 2; ++c){
      int aoff = (w*16 + r)*64 + c*32 + g*8;
      s16x8 a_h = *(const s16x8*)(A + aoff);
      #pragma unroll
      for (int j = 0; j < 4; ++j){
        s16x8 b_h = *(const s16x8*)(B + (j*16 + r)*64 + c*32 + g*8);
        acc[j] = MFMA(a_h, b_h, acc[j]);
      }
    }
    __syncthreads();
    cur ^= 1;
  }

  #pragma unroll
  for (int j = 0; j < 4; ++j){
    #pragma unroll
    for (int e = 0; e < 4; ++e){
      int m = tm*64 + w*16 + g*4 + e;
      int n = tn*64 + j*16 + r;
      float v = acc[j][e] + bias[n];
      int b = m >> 11, s = m & 2047;
      if (seg == 0){
        v *= qscale;
        __hip_bfloat16 h, l; split2(v, h, l);
        size_t idx = ((size_t)(b*12 + (n>>6))*2048 + s)*64 + (n & 63);
        qhp[idx] = h; qlp[idx] = l;
      } else if (seg == 1){
        size_t idx = ((size_t)(b*12 + (n>>6))*2048 + s)*64 + (n & 63);
        khp[idx] = __float2bfloat16(v);
      } else {
        size_t idx = ((size_t)(b*12 + (n>>6))*64 + (n & 63))*2048 + s;
        vTp[idx] = __float2bfloat16(v);
      }
    }
  }
}

// ---------------- out-proj GEMM: attn[4096x768] x Wo[768x768]^T + bo -> fp32 (3-term) ----------------
__global__ __launch_bounds__(256) void gemm_o(
    const __hip_bfloat16* __restrict__ Ah, const __hip_bfloat16* __restrict__ Al,
    const __hip_bfloat16* __restrict__ Bh, const __hip_bfloat16* __restrict__ Bl,
    const float* __restrict__ bias, float* __restrict__ o_f)
{
  __shared__ __align__(16) __hip_bfloat16 sAh[64*64];
  __shared__ __align__(16) __hip_bfloat16 sAl[64*64];
  __shared__ __align__(16) __hip_bfloat16 sBh[64*64];
  __shared__ __align__(16) __hip_bfloat16 sBl[64*64];

  const int tid = threadIdx.x;
  const int w = tid >> 6, lane = tid & 63, r = lane & 15, g = lane >> 4;
  const int t = blockIdx.x;
  const int tm = t / 12, tn = t % 12;

  const char* gA_h = (const char*)Ah + (size_t)tm*64*768*2;
  const char* gA_l = (const char*)Al + (size_t)tm*64*768*2;
  const char* gB_h = (const char*)Bh + (size_t)tn*64*768*2;
  const char* gB_l = (const char*)Bl + (size_t)tn*64*768*2;

  f32x4 acc[4] = {};

  for (int kb = 0; kb < 768; kb += 64){
    __syncthreads();
    #pragma unroll
    for (int i = 0; i < 2; ++i){
      int lb = i*4096 + tid*16;
      int row = lb >> 7, colb = lb & 127;
      gll16(gA_h + (size_t)row*1536 + kb*2 + colb, (char*)sAh + i*4096 + w*1024);
      gll16(gA_l + (size_t)row*1536 + kb*2 + colb, (char*)sAl + i*4096 + w*1024);
      gll16(gB_h + (size_t)row*1536 + kb*2 + colb, (char*)sBh + i*4096 + w*1024);
      gll16(gB_l + (size_t)row*1536 + kb*2 + colb, (char*)sBl + i*4096 + w*1024);
    }
    __syncthreads();
    #pragma unroll
    for (int c = 0; c < 2; ++c){
      int aoff = (w*16 + r)*64 + c*32 + g*8;
      s16x8 a_h = *(const s16x8*)(sAh + aoff);
      s16x8 a_l = *(const s16x8*)(sAl + aoff);
      #pragma unroll
      for (int j = 0; j < 4; ++j){
        int boff = (j*16 + r)*64 + c*32 + g*8;
        s16x8 b_h = *(const s16x8*)(sBh + boff);
        s16x8 b_l = *(const s16x8*)(sBl + boff);
        acc[j] = MFMA(a_h, b_h, acc[j]);
        acc[j] = MFMA(a_l, b_h, acc[j]);
        acc[j] = MFMA(a_h, b_l, acc[j]);
      }
    }
  }

  #pragma unroll
  for (int j = 0; j < 4; ++j){
    #pragma unroll
    for (int e = 0; e < 4; ++e){
      int m = tm*64 + w*16 + g*4 + e;
      int n = tn*64 + j*16 + r;
      o_f[(size_t)m*768 + n] = acc[j][e] + bias[n];
    }
  }
}

// ---------------- attn phase 1: softmax denominators (R13-exact) ----------------
// grid = 24 bh * 64 qt. 1-term QK, 2-deep K-register prefetch.
__global__ __launch_bounds__(256,4) void attn_l(
    const __hip_bfloat16* __restrict__ qh,
    const __hip_bfloat16* __restrict__ kh,
    float* __restrict__ rlbuf)
{
  __shared__ float ldsL[128];
  const int tid  = threadIdx.x;
  const int w    = tid >> 6;
  const int lane = tid & 63;
  const int col  = lane & 31;
  const int hi   = lane >> 5;
  const int bh = blockIdx.x % 24, qt = blockIdx.x / 24;

  const __hip_bfloat16* qr_h = qh + ((size_t)bh*2048 + qt*32 + col)*64 + hi*8;
  s16x8 Qh[4];
  #pragma unroll
  for (int ks = 0; ks < 4; ++ks) Qh[ks] = *(const s16x8*)(qr_h + ks*16);

  const __hip_bfloat16* kb = kh + (size_t)bh*2048*64;

  s16x8 kfn[4];
  {
    const __hip_bfloat16* kr = kb + ((size_t)(w*16)*32 + col)*64 + hi*8;
    #pragma unroll
    for (int ks = 0; ks < 4; ++ks) kfn[ks] = *(const s16x8*)(kr + ks*16);
  }

  float ps0=0.f, ps1=0.f, ps2=0.f, ps3=0.f;
  for (int c = 0; c < 16; ++c){
    s16x8 kf[4];
    #pragma unroll
    for (int ks = 0; ks < 4; ++ks) kf[ks] = kfn[ks];
    if (c < 15){
      const __hip_bfloat16* kr = kb + ((size_t)(w*16 + c + 1)*32 + col)*64 + hi*8;
      #pragma unroll
      for (int ks = 0; ks < 4; ++ks) kfn[ks] = *(const s16x8*)(kr + ks*16);
    }
    f32x16 s0;
    #pragma unroll
    for (int e = 0; e < 16; ++e) s0[e] = 0.f;
    #pragma unroll
    for (int ks = 0; ks < 4; ++ks) s0 = MFMA32(kf[ks], Qh[ks], s0);
    #pragma unroll
    for (int e = 0; e < 16; e += 4){
      ps0 += exp2f(s0[e+0]); ps1 += exp2f(s0[e+1]);
      ps2 += exp2f(s0[e+2]); ps3 += exp2f(s0[e+3]);
    }
  }
  float l_w = (ps0+ps1) + (ps2+ps3);
  l_w += __shfl_xor(l_w, 32);
  if (lane < 32) ldsL[w*32 + col] = l_w;
  __syncthreads();
  if (tid < 32){
    float lt = (ldsL[tid] + ldsL[32+tid]) + (ldsL[64+tid] + ldsL[96+tid]);
    rlbuf[(size_t)bh*2048 + qt*32 + tid] = 1.0f / lt;
  }
}

// ---------------- attn phase 2: weights + PV (R13 store-early order) ----------------
// 2-term QK, 2-deep K prefetch. __launch_bounds__(256,3): live set ~150 VGPR exceeds
// the 128 cap of (256,4), which forced remat/spill (R14/R15 lesson); cap 168 keeps
// the prefetch real. Store-early (store-late measured +14us, R15).
__global__ __launch_bounds__(256,3) void attn_pv(
    const __hip_bfloat16* __restrict__ qh, const __hip_bfloat16* __restrict__ ql,
    const __hip_bfloat16* __restrict__ kh,
    const __hip_bfloat16* __restrict__ vT,
    const float* __restrict__ rlbuf,
    float* __restrict__ wout,
    __hip_bfloat16* __restrict__ attnh, __hip_bfloat16* __restrict__ attnl)
{
  __shared__ __align__(16) float ldsX[4*32*36];   // 18 KB: per-wave W scratch / PV merge
  __shared__ float ldsRL[32];

  const int tid  = threadIdx.x;
  const int w    = tid >> 6;
  const int lane = tid & 63;
  const int col  = lane & 31;
  const int hi   = lane >> 5;
  const int bh = blockIdx.x % 24, qt = blockIdx.x / 24;

  const __hip_bfloat16* qr_h = qh + ((size_t)bh*2048 + qt*32 + col)*64 + hi*8;
  const __hip_bfloat16* qr_l = ql + ((size_t)bh*2048 + qt*32 + col)*64 + hi*8;
  s16x8 Qh[4], Ql[4];
  #pragma unroll
  for (int ks = 0; ks < 4; ++ks){
    Qh[ks] = *(const s16x8*)(qr_h + ks*16);
    Ql[ks] = *(const s16x8*)(qr_l + ks*16);
  }

  if (tid < 32) ldsRL[tid] = rlbuf[(size_t)bh*2048 + qt*32 + tid];
  __syncthreads();
  const float rl = ldsRL[col];

  const __hip_bfloat16* kb = kh + (size_t)bh*2048*64;     // [key][64]
  const __hip_bfloat16* vb = vT + (size_t)bh*64*2048;     // [d][key]
  float* W = ldsX + w*1152;                               // 32 x 36 floats

  s16x8 kfn[4];
  {
    const __hip_bfloat16* kr = kb + ((size_t)(w*16)*32 + col)*64 + hi*8;
    #pragma unroll
    for (int ks = 0; ks < 4; ++ks) kfn[ks] = *(const s16x8*)(kr + ks*16);
  }

  f32x16 pv0, pv1;
  #pragma unroll
  for (int e = 0; e < 16; ++e){ pv0[e]=0.f; pv1[e]=0.f; }
  float* wq = wout + ((size_t)bh*2048 + (size_t)qt*32)*2048;

  for (int c = 0; c < 16; ++c){
    const int key0 = (w*16 + c)*32;
    s16x8 kf[4];
    #pragma unroll
    for (int ks = 0; ks < 4; ++ks) kf[ks] = kfn[ks];
    if (c < 15){
      const __hip_bfloat16* kr = kb + ((size_t)(w*16 + c + 1)*32 + col)*64 + hi*8;
      #pragma unroll
      for (int ks = 0; ks < 4; ++ks) kfn[ks] = *(const s16x8*)(kr + ks*16);
    }
    s16x8 vv[2][2];
    #pragma unroll
    for (int ww = 0; ww < 2; ++ww)
      #pragma unroll
      for (int dt = 0; dt < 2; ++dt)
        vv[ww][dt] = *(const s16x8*)(vb + ((size_t)(dt*32+col)*2048 + key0 + ww*16 + hi*8));

    f32x16 s0;
    #pragma unroll
    for (int e = 0; e < 16; ++e) s0[e] = 0.f;
    #pragma unroll
    for (int ks = 0; ks < 4; ++ks){
      s0 = MFMA32(kf[ks], Qh[ks], s0);
      s0 = MFMA32(kf[ks], Ql[ks], s0);
    }
    #pragma unroll
    for (int e = 0; e < 16; ++e) s0[e] = exp2f(s0[e]);   // unnormalized p, q-row = col

    // ---- normalized weights -> LDS (transpose) -> coalesced global ----
    #pragma unroll
    for (int rq = 0; rq < 4; ++rq){
      f32x4 f;
      f[0]=s0[rq*4+0]*rl; f[1]=s0[rq*4+1]*rl; f[2]=s0[rq*4+2]*rl; f[3]=s0[rq*4+3]*rl;
      *(f32x4*)(W + col*36 + rq*8 + hi*4) = f;           // key idx rq*8+hi*4+j
    }
    #pragma unroll
    for (int it = 0; it < 4; ++it){
      int q  = it*8 + (lane>>3);
      int k4 = (lane&7)*4;
      f32x4 f = *(const f32x4*)(W + q*36 + k4);
      *(f32x4*)(wq + (size_t)q*2048 + key0 + k4) = f;    // 8 rows x 128B per instr
    }

    // ---- pack p -> bf16 A-frags, PV ----
    #pragma unroll
    for (int ww = 0; ww < 2; ++ww){
      const int e0 = ww*8;
      unsigned wa = pack2(s0[e0+0], s0[e0+1]);
      unsigned wb = pack2(s0[e0+2], s0[e0+3]);
      unsigned wc = pack2(s0[e0+4], s0[e0+5]);
      unsigned wd = pack2(s0[e0+6], s0[e0+7]);
      plane32swap(wa, wc);
      plane32swap(wb, wd);
      union { unsigned u[4]; s16x8 v; } cv;
      cv.u[0]=wa; cv.u[1]=wb; cv.u[2]=wc; cv.u[3]=wd;
      pv0 = MFMA32(cv.v, vv[ww][0], pv0);
      pv1 = MFMA32(cv.v, vv[ww][1], pv1);
    }
  }

  __syncthreads();   // ldsX transitions from W-scratch to PV-merge buffer

  float* ldsPV = ldsX;
  if (w >= 2){
    const int buf = w - 2;
    #pragma unroll
    for (int e = 0; e < 16; ++e){
      ldsPV[(e)   *128 + buf*64 + lane] = pv0[e];
      ldsPV[(16+e)*128 + buf*64 + lane] = pv1[e];
    }
  }
  __syncthreads();
  if (w < 2){
    #pragma unroll
    for (int e = 0; e < 16; ++e){
      pv0[e] += ldsPV[(e)   *128 + w*64 + lane];
      pv1[e] += ldsPV[(16+e)*128 + w*64 + lane];
    }
  }
  __syncthreads();
  if (w == 1){
    #pragma unroll
    for (int e = 0; e < 16; ++e){
      ldsPV[(e)   *128 + lane] = pv0[e];
      ldsPV[(16+e)*128 + lane] = pv1[e];
    }
  }
  __syncthreads();
  if (w == 0){
    #pragma unroll
    for (int e = 0; e < 16; ++e){
      pv0[e] += ldsPV[(e)   *128 + lane];
      pv1[e] += ldsPV[(16+e)*128 + lane];
    }
    const int b_ = bh / 12, hh = bh % 12;
    #pragma unroll
    for (int e = 0; e < 16; ++e){
      int qsub = (e&3) + 8*(e>>2) + 4*hi;        // q-row of THIS register (PV D-layout)
      float re = ldsRL[qsub];
      int qrow = qt*32 + qsub;
      size_t base = ((size_t)b_*2048 + qrow)*768 + hh*64;
      __hip_bfloat16 h0, l0, h1, l1;
      split2(pv0[e]*re, h0, l0);
      split2(pv1[e]*re, h1, l1);
      attnh[base + col]      = h0; attnl[base + col]      = l0;
      attnh[base + 32 + col] = h1; attnl[base + 32 + col] = l1;
    }
  }
}

// ---------------- launch ----------------
extern "C" void kernel_launch(void* const* d_in, const int* in_sizes, int n_in,
                              void* d_out, int out_size, void* d_ws, size_t ws_size,
                              hipStream_t stream){
  const float* Q  = (const float*)d_in[0];
  const float* Kx = (const float*)d_in[1];
  const float* V  = (const float*)d_in[2];
  const float* Wq = (const float*)d_in[3];
  const float* bq = (const float*)d_in[4];
  const float* Wk = (const float*)d_in[5];
  const float* bk = (const float*)d_in[6];
  const float* Wv = (const float*)d_in[7];
  const float* bv = (const float*)d_in[8];
  const float* Wo = (const float*)d_in[9];
  const float* bo = (const float*)d_in[10];

  float* out = (float*)d_out;
  float* wts = out + (size_t)2*2048*768;

  char* cur = (char*)d_ws;
  auto alloc = [&](size_t elems)->__hip_bfloat16*{
    __hip_bfloat16* p = (__hip_bfloat16*)cur;
    cur += ((elems*2 + 255) & ~(size_t)255);
    return p;
  };
  const size_t NE = (size_t)4096*768;
  const size_t WE = (size_t)768*768;

  __hip_bfloat16 *QIh=alloc(NE), *KIh=alloc(NE), *VIh=alloc(NE);
  __hip_bfloat16 *Wqh=alloc(WE), *Wkh=alloc(WE), *Wvh=alloc(WE),
                 *Woh=alloc(WE), *Wol=alloc(WE);
  __hip_bfloat16 *qhp=alloc(NE), *qlp=alloc(NE), *khp=alloc(NE),
                 *vTp=alloc(NE);
  __hip_bfloat16 *ath=alloc(NE), *atl=alloc(NE);
  float* rlbuf = (float*)alloc(2*24*2048);   // 49152 floats

  split_all<<<11520, 256, 0, stream>>>(Q, Kx, V, Wq, Wk, Wv, Wo,
      QIh, KIh, VIh, Wqh, Wkh, Wvh, Woh, Wol);

  // log2-domain softmax: bake log2(e)/8 into the Q projection scale
  gemm_qkv<<<2304, 256, 0, stream>>>(
      QIh, KIh, VIh,
      Wqh, Wkh, Wvh,
      bq, bk, bv, 0.18033688011112042f,
      qhp, qlp, khp, vTp);

  attn_l <<<1536, 256, 0, stream>>>(qhp, khp, rlbuf);
  attn_pv<<<1536, 256, 0, stream>>>(qhp, qlp, khp, vTp, rlbuf, wts, ath, atl);

  gemm_o<<<768, 256, 0, stream>>>(ath,atl,Woh,Wol,bo, out);
}

// Round 17
// 241.711 us; speedup vs baseline: 1.3706x; 1.0579x over previous
//
#include <hip/hip_runtime.h>
#include <hip/hip_bf16.h>

typedef __attribute__((ext_vector_type(4)))  float f32x4;
typedef __attribute__((ext_vector_type(16))) float f32x16;
typedef __attribute__((ext_vector_type(8)))  short s16x8;

#define MFMA(a,b,c)   __builtin_amdgcn_mfma_f32_16x16x32_bf16(a,b,c,0,0,0)
#define MFMA32(a,b,c) __builtin_amdgcn_mfma_f32_32x32x16_bf16(a,b,c,0,0,0)

__device__ __forceinline__ void gll16(const void* gptr, void* lptr){
  auto g = (const __attribute__((address_space(1))) unsigned int*)gptr;
  auto l = (__attribute__((address_space(3))) unsigned int*)lptr;
  __builtin_amdgcn_global_load_lds(g, l, 16, 0, 0);
}

__device__ __forceinline__ void split2(float x, __hip_bfloat16& h, __hip_bfloat16& l){
  h = __float2bfloat16(x);
  l = __float2bfloat16(x - __bfloat162float(h));
}

__device__ __forceinline__ unsigned short bf16bits(float x){
  __hip_bfloat16 h = __float2bfloat16(x);
  return *reinterpret_cast<unsigned short*>(&h);
}
__device__ __forceinline__ unsigned pack2(float lo, float hi){
  return (unsigned)bf16bits(lo) | ((unsigned)bf16bits(hi) << 16);
}
__device__ __forceinline__ void plane32swap(unsigned &a, unsigned &b){
  asm volatile("v_permlane32_swap_b32 %0, %1" : "+v"(a), "+v"(b));
}

// ---------------- fused input split: fp32 -> bf16 (hi; lo only for Wo) ----------------
__global__ __launch_bounds__(256) void split_all(
  const float* __restrict__ Q, const float* __restrict__ K, const float* __restrict__ V,
  const float* __restrict__ Wq, const float* __restrict__ Wk,
  const float* __restrict__ Wv, const float* __restrict__ Wo,
  __hip_bfloat16* __restrict__ QIh,
  __hip_bfloat16* __restrict__ KIh,
  __hip_bfloat16* __restrict__ VIh,
  __hip_bfloat16* __restrict__ Wqh,
  __hip_bfloat16* __restrict__ Wkh,
  __hip_bfloat16* __restrict__ Wvh,
  __hip_bfloat16* __restrict__ Woh, __hip_bfloat16* __restrict__ Wol)
{
  const int NE4 = 786432, WE4 = 147456;
  int i = blockIdx.x*256 + threadIdx.x;
  const float* src; __hip_bfloat16 *dh, *dl = nullptr; int off;
  if (i < 3*NE4){
    int seg = i / NE4; off = i - seg*NE4;
    src = seg==0 ? Q   : (seg==1 ? K   : V);
    dh  = seg==0 ? QIh : (seg==1 ? KIh : VIh);
  } else {
    int j = i - 3*NE4; int seg = j / WE4; off = j - seg*WE4;
    src = seg==0 ? Wq  : (seg==1 ? Wk  : (seg==2 ? Wv  : Wo));
    dh  = seg==0 ? Wqh : (seg==1 ? Wkh : (seg==2 ? Wvh : Woh));
    if (seg == 3) dl = Wol;
  }
  float4 x = ((const float4*)src)[off];
  __hip_bfloat16 h0,l0,h1,l1,h2,l2,h3,l3;
  split2(x.x,h0,l0); split2(x.y,h1,l1); split2(x.z,h2,l2); split2(x.w,h3,l3);
  union { __hip_bfloat16 b[4]; ushort4 u; } H, L;
  H.b[0]=h0; H.b[1]=h1; H.b[2]=h2; H.b[3]=h3;
  L.b[0]=l0; L.b[1]=l1; L.b[2]=l2; L.b[3]=l3;
  *(ushort4*)(dh + (size_t)off*4) = H.u;
  if (dl) *(ushort4*)(dl + (size_t)off*4) = L.u;
}

// ---------------- fused QKV GEMM: uniform 1-term, 2-phase double-buffered ----------------
__global__ __launch_bounds__(256) void gemm_qkv(
    const __hip_bfloat16* __restrict__ QAh,
    const __hip_bfloat16* __restrict__ KAh,
    const __hip_bfloat16* __restrict__ VAh,
    const __hip_bfloat16* __restrict__ WqH,
    const __hip_bfloat16* __restrict__ WkH,
    const __hip_bfloat16* __restrict__ WvH,
    const float* __restrict__ bq, const float* __restrict__ bk, const float* __restrict__ bv,
    float qscale,
    __hip_bfloat16* __restrict__ qhp, __hip_bfloat16* __restrict__ qlp,
    __hip_bfloat16* __restrict__ khp, __hip_bfloat16* __restrict__ vTp)
{
  __shared__ __align__(16) __hip_bfloat16 lds[16384];   // 32 KB: 2 bufs x (A 8KB + B 8KB)

  const int tid = threadIdx.x;
  const int w = tid >> 6, lane = tid & 63, r = lane & 15, g = lane >> 4;
  const int wg = blockIdx.x;
  const int seg = wg / 768;
  const int t = wg % 768;
  const int tm = t / 12, tn = t % 12;

  const __hip_bfloat16* Ah = seg==0 ? QAh : (seg==1 ? KAh : VAh);
  const __hip_bfloat16* Bh = seg==0 ? WqH : (seg==1 ? WkH : WvH);
  const float* bias        = seg==0 ? bq  : (seg==1 ? bk  : bv);

  const char* gA_h = (const char*)Ah + (size_t)tm*64*768*2;
  const char* gB_h = (const char*)Bh + (size_t)tn*64*768*2;

  f32x4 acc[4] = {};

  auto stage = [&](int buf, int kbe){
    #pragma unroll
    for (int i = 0; i < 2; ++i){
      int lb = i*4096 + tid*16;
      int row = lb >> 7, colb = lb & 127;
      gll16(gA_h + (size_t)row*1536 + kbe*2 + colb, (char*)lds + buf*16384 + i*4096 + w*1024);
      gll16(gB_h + (size_t)row*1536 + kbe*2 + colb, (char*)lds + buf*16384 + 8192 + i*4096 + w*1024);
    }
  };
  int cur = 0;
  stage(0, 0);
  __syncthreads();
  for (int it = 0; it < 12; ++it){
    if (it + 1 < 12) stage(cur ^ 1, (it+1)*64);
    const __hip_bfloat16* A = lds + cur*8192;
    const __hip_bfloat16* B = lds + cur*8192 + 4096;
    #pragma unroll
    for (int c = 0; c < 2; ++c){
      int aoff = (w*16 + r)*64 + c*32 + g*8;
      s16x8 a_h = *(const s16x8*)(A + aoff);
      #pragma unroll
      for (int j = 0; j < 4; ++j){
        s16x8 b_h = *(const s16x8*)(B + (j*16 + r)*64 + c*32 + g*8);
        acc[j] = MFMA(a_h, b_h, acc[j]);
      }
    }
    __syncthreads();
    cur ^= 1;
  }

  #pragma unroll
  for (int j = 0; j < 4; ++j){
    #pragma unroll
    for (int e = 0; e < 4; ++e){
      int m = tm*64 + w*16 + g*4 + e;
      int n = tn*64 + j*16 + r;
      float v = acc[j][e] + bias[n];
      int b = m >> 11, s = m & 2047;
      if (seg == 0){
        v *= qscale;
        __hip_bfloat16 h, l; split2(v, h, l);
        size_t idx = ((size_t)(b*12 + (n>>6))*2048 + s)*64 + (n & 63);
        qhp[idx] = h; qlp[idx] = l;
      } else if (seg == 1){
        size_t idx = ((size_t)(b*12 + (n>>6))*2048 + s)*64 + (n & 63);
        khp[idx] = __float2bfloat16(v);
      } else {
        size_t idx = ((size_t)(b*12 + (n>>6))*64 + (n & 63))*2048 + s;
        vTp[idx] = __float2bfloat16(v);
      }
    }
  }
}

// ---------------- out-proj GEMM: attn[4096x768] x Wo[768x768]^T + bo -> fp32 (3-term) ----------------
__global__ __launch_bounds__(256) void gemm_o(
    const __hip_bfloat16* __restrict__ Ah, const __hip_bfloat16* __restrict__ Al,
    const __hip_bfloat16* __restrict__ Bh, const __hip_bfloat16* __restrict__ Bl,
    const float* __restrict__ bias, float* __restrict__ o_f)
{
  __shared__ __align__(16) __hip_bfloat16 sAh[64*64];
  __shared__ __align__(16) __hip_bfloat16 sAl[64*64];
  __shared__ __align__(16) __hip_bfloat16 sBh[64*64];
  __shared__ __align__(16) __hip_bfloat16 sBl[64*64];

  const int tid = threadIdx.x;
  const int w = tid >> 6, lane = tid & 63, r = lane & 15, g = lane >> 4;
  const int t = blockIdx.x;
  const int tm = t / 12, tn = t % 12;

  const char* gA_h = (const char*)Ah + (size_t)tm*64*768*2;
  const char* gA_l = (const char*)Al + (size_t)tm*64*768*2;
  const char* gB_h = (const char*)Bh + (size_t)tn*64*768*2;
  const char* gB_l = (const char*)Bl + (size_t)tn*64*768*2;

  f32x4 acc[4] = {};

  for (int kb = 0; kb < 768; kb += 64){
    __syncthreads();
    #pragma unroll
    for (int i = 0; i < 2; ++i){
      int lb = i*4096 + tid*16;
      int row = lb >> 7, colb = lb & 127;
      gll16(gA_h + (size_t)row*1536 + kb*2 + colb, (char*)sAh + i*4096 + w*1024);
      gll16(gA_l + (size_t)row*1536 + kb*2 + colb, (char*)sAl + i*4096 + w*1024);
      gll16(gB_h + (size_t)row*1536 + kb*2 + colb, (char*)sBh + i*4096 + w*1024);
      gll16(gB_l + (size_t)row*1536 + kb*2 + colb, (char*)sBl + i*4096 + w*1024);
    }
    __syncthreads();
    #pragma unroll
    for (int c = 0; c < 2; ++c){
      int aoff = (w*16 + r)*64 + c*32 + g*8;
      s16x8 a_h = *(const s16x8*)(sAh + aoff);
      s16x8 a_l = *(const s16x8*)(sAl + aoff);
      #pragma unroll
      for (int j = 0; j < 4; ++j){
        int boff = (j*16 + r)*64 + c*32 + g*8;
        s16x8 b_h = *(const s16x8*)(sBh + boff);
        s16x8 b_l = *(const s16x8*)(sBl + boff);
        acc[j] = MFMA(a_h, b_h, acc[j]);
        acc[j] = MFMA(a_l, b_h, acc[j]);
        acc[j] = MFMA(a_h, b_l, acc[j]);
      }
    }
  }

  #pragma unroll
  for (int j = 0; j < 4; ++j){
    #pragma unroll
    for (int e = 0; e < 4; ++e){
      int m = tm*64 + w*16 + g*4 + e;
      int n = tn*64 + j*16 + r;
      o_f[(size_t)m*768 + n] = acc[j][e] + bias[n];
    }
  }
}

// ---------------- attn phase 1: softmax denominators ----------------
// grid = 24 bh * 32 qt2 (64 q-rows/block): each K-fragment feeds TWO q-tiles' MFMAs
// (2x K-traffic amortization). __launch_bounds__(256,3): the R14 version of this
// spilled at the (256,4)=128-VGPR cap (live set ~115+); cap 168 fits (R16 lesson).
__global__ __launch_bounds__(256,3) void attn_l(
    const __hip_bfloat16* __restrict__ qh,
    const __hip_bfloat16* __restrict__ kh,
    float* __restrict__ rlbuf)
{
  __shared__ float ldsL[2][128];
  const int tid  = threadIdx.x;
  const int w    = tid >> 6;
  const int lane = tid & 63;
  const int col  = lane & 31;
  const int hi   = lane >> 5;
  const int bh = blockIdx.x % 24, qt2 = blockIdx.x / 24;

  const __hip_bfloat16* qr0 = qh + ((size_t)bh*2048 + qt2*64 + col)*64 + hi*8;
  const __hip_bfloat16* qr1 = qr0 + 32*64;
  s16x8 Qh0[4], Qh1[4];
  #pragma unroll
  for (int ks = 0; ks < 4; ++ks){
    Qh0[ks] = *(const s16x8*)(qr0 + ks*16);
    Qh1[ks] = *(const s16x8*)(qr1 + ks*16);
  }

  const __hip_bfloat16* kb = kh + (size_t)bh*2048*64;

  s16x8 kfn[4];
  {
    const __hip_bfloat16* kr = kb + ((size_t)(w*16)*32 + col)*64 + hi*8;
    #pragma unroll
    for (int ks = 0; ks < 4; ++ks) kfn[ks] = *(const s16x8*)(kr + ks*16);
  }

  float pa0=0.f, pa1=0.f, pa2=0.f, pa3=0.f;   // tile0 partial sums
  float pb0=0.f, pb1=0.f, pb2=0.f, pb3=0.f;   // tile1
  for (int c = 0; c < 16; ++c){
    s16x8 kf[4];
    #pragma unroll
    for (int ks = 0; ks < 4; ++ks) kf[ks] = kfn[ks];
    if (c < 15){
      const __hip_bfloat16* kr = kb + ((size_t)(w*16 + c + 1)*32 + col)*64 + hi*8;
      #pragma unroll
      for (int ks = 0; ks < 4; ++ks) kfn[ks] = *(const s16x8*)(kr + ks*16);
    }
    f32x16 s0, s1;
    #pragma unroll
    for (int e = 0; e < 16; ++e){ s0[e] = 0.f; s1[e] = 0.f; }
    #pragma unroll
    for (int ks = 0; ks < 4; ++ks){
      s0 = MFMA32(kf[ks], Qh0[ks], s0);
      s1 = MFMA32(kf[ks], Qh1[ks], s1);
    }
    #pragma unroll
    for (int e = 0; e < 16; e += 4){
      pa0 += exp2f(s0[e+0]); pa1 += exp2f(s0[e+1]);
      pa2 += exp2f(s0[e+2]); pa3 += exp2f(s0[e+3]);
      pb0 += exp2f(s1[e+0]); pb1 += exp2f(s1[e+1]);
      pb2 += exp2f(s1[e+2]); pb3 += exp2f(s1[e+3]);
    }
  }
  float l0 = (pa0+pa1) + (pa2+pa3);
  float l1 = (pb0+pb1) + (pb2+pb3);
  l0 += __shfl_xor(l0, 32);
  l1 += __shfl_xor(l1, 32);
  if (lane < 32){
    ldsL[0][w*32 + col] = l0;
    ldsL[1][w*32 + col] = l1;
  }
  __syncthreads();
  if (tid < 64){
    int tt = tid >> 5, q = tid & 31;
    float lt = (ldsL[tt][q] + ldsL[tt][32+q]) + (ldsL[tt][64+q] + ldsL[tt][96+q]);
    rlbuf[(size_t)bh*2048 + qt2*64 + tt*32 + q] = 1.0f / lt;
  }
}

// ---------------- attn phase 2: weights + PV (R16-exact) ----------------
__global__ __launch_bounds__(256,3) void attn_pv(
    const __hip_bfloat16* __restrict__ qh, const __hip_bfloat16* __restrict__ ql,
    const __hip_bfloat16* __restrict__ kh,
    const __hip_bfloat16* __restrict__ vT,
    const float* __restrict__ rlbuf,
    float* __restrict__ wout,
    __hip_bfloat16* __restrict__ attnh, __hip_bfloat16* __restrict__ attnl)
{
  __shared__ __align__(16) float ldsX[4*32*36];   // 18 KB: per-wave W scratch / PV merge
  __shared__ float ldsRL[32];

  const int tid  = threadIdx.x;
  const int w    = tid >> 6;
  const int lane = tid & 63;
  const int col  = lane & 31;
  const int hi   = lane >> 5;
  const int bh = blockIdx.x % 24, qt = blockIdx.x / 24;

  const __hip_bfloat16* qr_h = qh + ((size_t)bh*2048 + qt*32 + col)*64 + hi*8;
  const __hip_bfloat16* qr_l = ql + ((size_t)bh*2048 + qt*32 + col)*64 + hi*8;
  s16x8 Qh[4], Ql[4];
  #pragma unroll
  for (int ks = 0; ks < 4; ++ks){
    Qh[ks] = *(const s16x8*)(qr_h + ks*16);
    Ql[ks] = *(const s16x8*)(qr_l + ks*16);
  }

  if (tid < 32) ldsRL[tid] = rlbuf[(size_t)bh*2048 + qt*32 + tid];
  __syncthreads();
  const float rl = ldsRL[col];

  const __hip_bfloat16* kb = kh + (size_t)bh*2048*64;     // [key][64]
  const __hip_bfloat16* vb = vT + (size_t)bh*64*2048;     // [d][key]
  float* W = ldsX + w*1152;                               // 32 x 36 floats

  s16x8 kfn[4];
  {
    const __hip_bfloat16* kr = kb + ((size_t)(w*16)*32 + col)*64 + hi*8;
    #pragma unroll
    for (int ks = 0; ks < 4; ++ks) kfn[ks] = *(const s16x8*)(kr + ks*16);
  }

  f32x16 pv0, pv1;
  #pragma unroll
  for (int e = 0; e < 16; ++e){ pv0[e]=0.f; pv1[e]=0.f; }
  float* wq = wout + ((size_t)bh*2048 + (size_t)qt*32)*2048;

  for (int c = 0; c < 16; ++c){
    const int key0 = (w*16 + c)*32;
    s16x8 kf[4];
    #pragma unroll
    for (int ks = 0; ks < 4; ++ks) kf[ks] = kfn[ks];
    if (c < 15){
      const __hip_bfloat16* kr = kb + ((size_t)(w*16 + c + 1)*32 + col)*64 + hi*8;
      #pragma unroll
      for (int ks = 0; ks < 4; ++ks) kfn[ks] = *(const s16x8*)(kr + ks*16);
    }
    s16x8 vv[2][2];
    #pragma unroll
    for (int ww = 0; ww < 2; ++ww)
      #pragma unroll
      for (int dt = 0; dt < 2; ++dt)
        vv[ww][dt] = *(const s16x8*)(vb + ((size_t)(dt*32+col)*2048 + key0 + ww*16 + hi*8));

    f32x16 s0;
    #pragma unroll
    for (int e = 0; e < 16; ++e) s0[e] = 0.f;
    #pragma unroll
    for (int ks = 0; ks < 4; ++ks){
      s0 = MFMA32(kf[ks], Qh[ks], s0);
      s0 = MFMA32(kf[ks], Ql[ks], s0);
    }
    #pragma unroll
    for (int e = 0; e < 16; ++e) s0[e] = exp2f(s0[e]);   // unnormalized p, q-row = col

    // ---- normalized weights -> LDS (transpose) -> coalesced global ----
    #pragma unroll
    for (int rq = 0; rq < 4; ++rq){
      f32x4 f;
      f[0]=s0[rq*4+0]*rl; f[1]=s0[rq*4+1]*rl; f[2]=s0[rq*4+2]*rl; f[3]=s0[rq*4+3]*rl;
      *(f32x4*)(W + col*36 + rq*8 + hi*4) = f;           // key idx rq*8+hi*4+j
    }
    #pragma unroll
    for (int it = 0; it < 4; ++it){
      int q  = it*8 + (lane>>3);
      int k4 = (lane&7)*4;
      f32x4 f = *(const f32x4*)(W + q*36 + k4);
      *(f32x4*)(wq + (size_t)q*2048 + key0 + k4) = f;    // 8 rows x 128B per instr
    }

    // ---- pack p -> bf16 A-frags, PV ----
    #pragma unroll
    for (int ww = 0; ww < 2; ++ww){
      const int e0 = ww*8;
      unsigned wa = pack2(s0[e0+0], s0[e0+1]);
      unsigned wb = pack2(s0[e0+2], s0[e0+3]);
      unsigned wc = pack2(s0[e0+4], s0[e0+5]);
      unsigned wd = pack2(s0[e0+6], s0[e0+7]);
      plane32swap(wa, wc);
      plane32swap(wb, wd);
      union { unsigned u[4]; s16x8 v; } cv;
      cv.u[0]=wa; cv.u[1]=wb; cv.u[2]=wc; cv.u[3]=wd;
      pv0 = MFMA32(cv.v, vv[ww][0], pv0);
      pv1 = MFMA32(cv.v, vv[ww][1], pv1);
    }
  }

  __syncthreads();   // ldsX transitions from W-scratch to PV-merge buffer

  float* ldsPV = ldsX;
  if (w >= 2){
    const int buf = w - 2;
    #pragma unroll
    for (int e = 0; e < 16; ++e){
      ldsPV[(e)   *128 + buf*64 + lane] = pv0[e];
      ldsPV[(16+e)*128 + buf*64 + lane] = pv1[e];
    }
  }
  __syncthreads();
  if (w < 2){
    #pragma unroll
    for (int e = 0; e < 16; ++e){
      pv0[e] += ldsPV[(e)   *128 + w*64 + lane];
      pv1[e] += ldsPV[(16+e)*128 + w*64 + lane];
    }
  }
  __syncthreads();
  if (w == 1){
    #pragma unroll
    for (int e = 0; e < 16; ++e){
      ldsPV[(e)   *128 + lane] = pv0[e];
      ldsPV[(16+e)*128 + lane] = pv1[e];
    }
  }
  __syncthreads();
  if (w == 0){
    #pragma unroll
    for (int e = 0; e < 16; ++e){
      pv0[e] += ldsPV[(e)   *128 + lane];
      pv1[e] += ldsPV[(16+e)*128 + lane];
    }
    const int b_ = bh / 12, hh = bh % 12;
    #pragma unroll
    for (int e = 0; e < 16; ++e){
      int qsub = (e&3) + 8*(e>>2) + 4*hi;        // q-row of THIS register (PV D-layout)
      float re = ldsRL[qsub];
      int qrow = qt*32 + qsub;
      size_t base = ((size_t)b_*2048 + qrow)*768 + hh*64;
      __hip_bfloat16 h0, l0, h1, l1;
      split2(pv0[e]*re, h0, l0);
      split2(pv1[e]*re, h1, l1);
      attnh[base + col]      = h0; attnl[base + col]      = l0;
      attnh[base + 32 + col] = h1; attnl[base + 32 + col] = l1;
    }
  }
}

// ---------------- launch ----------------
extern "C" void kernel_launch(void* const* d_in, const int* in_sizes, int n_in,
                              void* d_out, int out_size, void* d_ws, size_t ws_size,
                              hipStream_t stream){
  const float* Q  = (const float*)d_in[0];
  const float* Kx = (const float*)d_in[1];
  const float* V  = (const float*)d_in[2];
  const float* Wq = (const float*)d_in[3];
  const float* bq = (const float*)d_in[4];
  const float* Wk = (const float*)d_in[5];
  const float* bk = (const float*)d_in[6];
  const float* Wv = (const float*)d_in[7];
  const float* bv = (const float*)d_in[8];
  const float* Wo = (const float*)d_in[9];
  const float* bo = (const float*)d_in[10];

  float* out = (float*)d_out;
  float* wts = out + (size_t)2*2048*768;

  char* cur = (char*)d_ws;
  auto alloc = [&](size_t elems)->__hip_bfloat16*{
    __hip_bfloat16* p = (__hip_bfloat16*)cur;
    cur += ((elems*2 + 255) & ~(size_t)255);
    return p;
  };
  const size_t NE = (size_t)4096*768;
  const size_t WE = (size_t)768*768;

  __hip_bfloat16 *QIh=alloc(NE), *KIh=alloc(NE), *VIh=alloc(NE);
  __hip_bfloat16 *Wqh=alloc(WE), *Wkh=alloc(WE), *Wvh=alloc(WE),
                 *Woh=alloc(WE), *Wol=alloc(WE);
  __hip_bfloat16 *qhp=alloc(NE), *qlp=alloc(NE), *khp=alloc(NE),
                 *vTp=alloc(NE);
  __hip_bfloat16 *ath=alloc(NE), *atl=alloc(NE);
  float* rlbuf = (float*)alloc(2*24*2048);   // 49152 floats

  split_all<<<11520, 256, 0, stream>>>(Q, Kx, V, Wq, Wk, Wv, Wo,
      QIh, KIh, VIh, Wqh, Wkh, Wvh, Woh, Wol);

  // log2-domain softmax: bake log2(e)/8 into the Q projection scale
  gemm_qkv<<<2304, 256, 0, stream>>>(
      QIh, KIh, VIh,
      Wqh, Wkh, Wvh,
      bq, bk, bv, 0.18033688011112042f,
      qhp, qlp, khp, vTp);

  attn_l <<<768,  256, 0, stream>>>(qhp, khp, rlbuf);
  attn_pv<<<1536, 256, 0, stream>>>(qhp, qlp, khp, vTp, rlbuf, wts, ath, atl);

  gemm_o<<<768, 256, 0, stream>>>(ath,atl,Woh,Wol,bo, out);
}

// Round 18
// 240.341 us; speedup vs baseline: 1.3785x; 1.0057x over previous
//
#include <hip/hip_runtime.h>
#include <hip/hip_bf16.h>

typedef __attribute__((ext_vector_type(4)))  float f32x4;
typedef __attribute__((ext_vector_type(16))) float f32x16;
typedef __attribute__((ext_vector_type(8)))  short s16x8;

#define MFMA(a,b,c)   __builtin_amdgcn_mfma_f32_16x16x32_bf16(a,b,c,0,0,0)
#define MFMA32(a,b,c) __builtin_amdgcn_mfma_f32_32x32x16_bf16(a,b,c,0,0,0)

__device__ __forceinline__ void gll16(const void* gptr, void* lptr){
  auto g = (const __attribute__((address_space(1))) unsigned int*)gptr;
  auto l = (__attribute__((address_space(3))) unsigned int*)lptr;
  __builtin_amdgcn_global_load_lds(g, l, 16, 0, 0);
}

__device__ __forceinline__ void split2(float x, __hip_bfloat16& h, __hip_bfloat16& l){
  h = __float2bfloat16(x);
  l = __float2bfloat16(x - __bfloat162float(h));
}

__device__ __forceinline__ unsigned short bf16bits(float x){
  __hip_bfloat16 h = __float2bfloat16(x);
  return *reinterpret_cast<unsigned short*>(&h);
}
__device__ __forceinline__ unsigned pack2(float lo, float hi){
  return (unsigned)bf16bits(lo) | ((unsigned)bf16bits(hi) << 16);
}
__device__ __forceinline__ void plane32swap(unsigned &a, unsigned &b){
  asm volatile("v_permlane32_swap_b32 %0, %1" : "+v"(a), "+v"(b));
}

// ---------------- fused input split: fp32 -> bf16 (hi; lo only for Wo) ----------------
__global__ __launch_bounds__(256) void split_all(
  const float* __restrict__ Q, const float* __restrict__ K, const float* __restrict__ V,
  const float* __restrict__ Wq, const float* __restrict__ Wk,
  const float* __restrict__ Wv, const float* __restrict__ Wo,
  __hip_bfloat16* __restrict__ QIh,
  __hip_bfloat16* __restrict__ KIh,
  __hip_bfloat16* __restrict__ VIh,
  __hip_bfloat16* __restrict__ Wqh,
  __hip_bfloat16* __restrict__ Wkh,
  __hip_bfloat16* __restrict__ Wvh,
  __hip_bfloat16* __restrict__ Woh, __hip_bfloat16* __restrict__ Wol)
{
  const int NE4 = 786432, WE4 = 147456;
  int i = blockIdx.x*256 + threadIdx.x;
  const float* src; __hip_bfloat16 *dh, *dl = nullptr; int off;
  if (i < 3*NE4){
    int seg = i / NE4; off = i - seg*NE4;
    src = seg==0 ? Q   : (seg==1 ? K   : V);
    dh  = seg==0 ? QIh : (seg==1 ? KIh : VIh);
  } else {
    int j = i - 3*NE4; int seg = j / WE4; off = j - seg*WE4;
    src = seg==0 ? Wq  : (seg==1 ? Wk  : (seg==2 ? Wv  : Wo));
    dh  = seg==0 ? Wqh : (seg==1 ? Wkh : (seg==2 ? Wvh : Woh));
    if (seg == 3) dl = Wol;
  }
  float4 x = ((const float4*)src)[off];
  __hip_bfloat16 h0,l0,h1,l1,h2,l2,h3,l3;
  split2(x.x,h0,l0); split2(x.y,h1,l1); split2(x.z,h2,l2); split2(x.w,h3,l3);
  union { __hip_bfloat16 b[4]; ushort4 u; } H, L;
  H.b[0]=h0; H.b[1]=h1; H.b[2]=h2; H.b[3]=h3;
  L.b[0]=l0; L.b[1]=l1; L.b[2]=l2; L.b[3]=l3;
  *(ushort4*)(dh + (size_t)off*4) = H.u;
  if (dl) *(ushort4*)(dl + (size_t)off*4) = L.u;
}

// ---------------- fused QKV GEMM: 1-term, 2-phase dbuf, BM=64 x BN=128 ----------------
// BN=128 halves A-panel re-reads (12 -> 6 consumer blocks per panel): A traffic
// 680 -> 340 MB. LDS 2 bufs x (A 8KB + B 16KB) = 48KB -> 3 blocks/CU (unchanged).
// Per-element MFMA order unchanged -> bit-exact vs BN=64. grid = 3 * 64 * 6 = 1152.
__global__ __launch_bounds__(256) void gemm_qkv(
    const __hip_bfloat16* __restrict__ QAh,
    const __hip_bfloat16* __restrict__ KAh,
    const __hip_bfloat16* __restrict__ VAh,
    const __hip_bfloat16* __restrict__ WqH,
    const __hip_bfloat16* __restrict__ WkH,
    const __hip_bfloat16* __restrict__ WvH,
    const float* __restrict__ bq, const float* __restrict__ bk, const float* __restrict__ bv,
    float qscale,
    __hip_bfloat16* __restrict__ qhp, __hip_bfloat16* __restrict__ qlp,
    __hip_bfloat16* __restrict__ khp, __hip_bfloat16* __restrict__ vTp)
{
  __shared__ __align__(16) __hip_bfloat16 lds[24576];   // 48 KB: 2 bufs x (A 8KB + B 16KB)

  const int tid = threadIdx.x;
  const int w = tid >> 6, lane = tid & 63, r = lane & 15, g = lane >> 4;
  const int wg = blockIdx.x;
  const int seg = wg / 384;
  const int t = wg % 384;
  const int tm = t / 6, tn = t % 6;

  const __hip_bfloat16* Ah = seg==0 ? QAh : (seg==1 ? KAh : VAh);
  const __hip_bfloat16* Bh = seg==0 ? WqH : (seg==1 ? WkH : WvH);
  const float* bias        = seg==0 ? bq  : (seg==1 ? bk  : bv);

  const char* gA_h = (const char*)Ah + (size_t)tm*64*768*2;
  const char* gB_h = (const char*)Bh + (size_t)tn*128*768*2;

  f32x4 acc[8] = {};

  auto stage = [&](int buf, int kbe){
    #pragma unroll
    for (int i = 0; i < 2; ++i){   // A: 64 rows x 128 B
      int lb = i*4096 + tid*16;
      int row = lb >> 7, colb = lb & 127;
      gll16(gA_h + (size_t)row*1536 + kbe*2 + colb, (char*)lds + buf*24576 + i*4096 + w*1024);
    }
    #pragma unroll
    for (int i = 0; i < 4; ++i){   // B: 128 rows x 128 B
      int lb = i*4096 + tid*16;
      int row = lb >> 7, colb = lb & 127;
      gll16(gB_h + (size_t)row*1536 + kbe*2 + colb, (char*)lds + buf*24576 + 8192 + i*4096 + w*1024);
    }
  };
  int cur = 0;
  stage(0, 0);
  __syncthreads();
  for (int it = 0; it < 12; ++it){
    if (it + 1 < 12) stage(cur ^ 1, (it+1)*64);
    const __hip_bfloat16* A = lds + cur*12288;
    const __hip_bfloat16* B = lds + cur*12288 + 4096;
    #pragma unroll
    for (int c = 0; c < 2; ++c){
      int aoff = (w*16 + r)*64 + c*32 + g*8;
      s16x8 a_h = *(const s16x8*)(A + aoff);
      #pragma unroll
      for (int j = 0; j < 8; ++j){
        s16x8 b_h = *(const s16x8*)(B + (j*16 + r)*64 + c*32 + g*8);
        acc[j] = MFMA(a_h, b_h, acc[j]);
      }
    }
    __syncthreads();
    cur ^= 1;
  }

  #pragma unroll
  for (int j = 0; j < 8; ++j){
    #pragma unroll
    for (int e = 0; e < 4; ++e){
      int m = tm*64 + w*16 + g*4 + e;   // row in [4096]
      int n = tn*128 + j*16 + r;        // out feature in [768]
      float v = acc[j][e] + bias[n];
      int b = m >> 11, s = m & 2047;
      if (seg == 0){
        v *= qscale;
        __hip_bfloat16 h, l; split2(v, h, l);
        size_t idx = ((size_t)(b*12 + (n>>6))*2048 + s)*64 + (n & 63);
        qhp[idx] = h; qlp[idx] = l;
      } else if (seg == 1){
        size_t idx = ((size_t)(b*12 + (n>>6))*2048 + s)*64 + (n & 63);
        khp[idx] = __float2bfloat16(v);
      } else {
        size_t idx = ((size_t)(b*12 + (n>>6))*64 + (n & 63))*2048 + s;
        vTp[idx] = __float2bfloat16(v);
      }
    }
  }
}

// ---------------- out-proj GEMM: attn[4096x768] x Wo[768x768]^T + bo -> fp32 (3-term) ----------------
__global__ __launch_bounds__(256) void gemm_o(
    const __hip_bfloat16* __restrict__ Ah, const __hip_bfloat16* __restrict__ Al,
    const __hip_bfloat16* __restrict__ Bh, const __hip_bfloat16* __restrict__ Bl,
    const float* __restrict__ bias, float* __restrict__ o_f)
{
  __shared__ __align__(16) __hip_bfloat16 sAh[64*64];
  __shared__ __align__(16) __hip_bfloat16 sAl[64*64];
  __shared__ __align__(16) __hip_bfloat16 sBh[64*64];
  __shared__ __align__(16) __hip_bfloat16 sBl[64*64];

  const int tid = threadIdx.x;
  const int w = tid >> 6, lane = tid & 63, r = lane & 15, g = lane >> 4;
  const int t = blockIdx.x;
  const int tm = t / 12, tn = t % 12;

  const char* gA_h = (const char*)Ah + (size_t)tm*64*768*2;
  const char* gA_l = (const char*)Al + (size_t)tm*64*768*2;
  const char* gB_h = (const char*)Bh + (size_t)tn*64*768*2;
  const char* gB_l = (const char*)Bl + (size_t)tn*64*768*2;

  f32x4 acc[4] = {};

  for (int kb = 0; kb < 768; kb += 64){
    __syncthreads();
    #pragma unroll
    for (int i = 0; i < 2; ++i){
      int lb = i*4096 + tid*16;
      int row = lb >> 7, colb = lb & 127;
      gll16(gA_h + (size_t)row*1536 + kb*2 + colb, (char*)sAh + i*4096 + w*1024);
      gll16(gA_l + (size_t)row*1536 + kb*2 + colb, (char*)sAl + i*4096 + w*1024);
      gll16(gB_h + (size_t)row*1536 + kb*2 + colb, (char*)sBh + i*4096 + w*1024);
      gll16(gB_l + (size_t)row*1536 + kb*2 + colb, (char*)sBl + i*4096 + w*1024);
    }
    __syncthreads();
    #pragma unroll
    for (int c = 0; c < 2; ++c){
      int aoff = (w*16 + r)*64 + c*32 + g*8;
      s16x8 a_h = *(const s16x8*)(sAh + aoff);
      s16x8 a_l = *(const s16x8*)(sAl + aoff);
      #pragma unroll
      for (int j = 0; j < 4; ++j){
        int boff = (j*16 + r)*64 + c*32 + g*8;
        s16x8 b_h = *(const s16x8*)(sBh + boff);
        s16x8 b_l = *(const s16x8*)(sBl + boff);
        acc[j] = MFMA(a_h, b_h, acc[j]);
        acc[j] = MFMA(a_l, b_h, acc[j]);
        acc[j] = MFMA(a_h, b_l, acc[j]);
      }
    }
  }

  #pragma unroll
  for (int j = 0; j < 4; ++j){
    #pragma unroll
    for (int e = 0; e < 4; ++e){
      int m = tm*64 + w*16 + g*4 + e;
      int n = tn*64 + j*16 + r;
      o_f[(size_t)m*768 + n] = acc[j][e] + bias[n];
    }
  }
}

// ---------------- attn phase 1: softmax denominators (R17-exact) ----------------
// grid = 24 bh * 32 qt2 (64 q-rows/block), __launch_bounds__(256,3).
__global__ __launch_bounds__(256,3) void attn_l(
    const __hip_bfloat16* __restrict__ qh,
    const __hip_bfloat16* __restrict__ kh,
    float* __restrict__ rlbuf)
{
  __shared__ float ldsL[2][128];
  const int tid  = threadIdx.x;
  const int w    = tid >> 6;
  const int lane = tid & 63;
  const int col  = lane & 31;
  const int hi   = lane >> 5;
  const int bh = blockIdx.x % 24, qt2 = blockIdx.x / 24;

  const __hip_bfloat16* qr0 = qh + ((size_t)bh*2048 + qt2*64 + col)*64 + hi*8;
  const __hip_bfloat16* qr1 = qr0 + 32*64;
  s16x8 Qh0[4], Qh1[4];
  #pragma unroll
  for (int ks = 0; ks < 4; ++ks){
    Qh0[ks] = *(const s16x8*)(qr0 + ks*16);
    Qh1[ks] = *(const s16x8*)(qr1 + ks*16);
  }

  const __hip_bfloat16* kb = kh + (size_t)bh*2048*64;

  s16x8 kfn[4];
  {
    const __hip_bfloat16* kr = kb + ((size_t)(w*16)*32 + col)*64 + hi*8;
    #pragma unroll
    for (int ks = 0; ks < 4; ++ks) kfn[ks] = *(const s16x8*)(kr + ks*16);
  }

  float pa0=0.f, pa1=0.f, pa2=0.f, pa3=0.f;
  float pb0=0.f, pb1=0.f, pb2=0.f, pb3=0.f;
  for (int c = 0; c < 16; ++c){
    s16x8 kf[4];
    #pragma unroll
    for (int ks = 0; ks < 4; ++ks) kf[ks] = kfn[ks];
    if (c < 15){
      const __hip_bfloat16* kr = kb + ((size_t)(w*16 + c + 1)*32 + col)*64 + hi*8;
      #pragma unroll
      for (int ks = 0; ks < 4; ++ks) kfn[ks] = *(const s16x8*)(kr + ks*16);
    }
    f32x16 s0, s1;
    #pragma unroll
    for (int e = 0; e < 16; ++e){ s0[e] = 0.f; s1[e] = 0.f; }
    #pragma unroll
    for (int ks = 0; ks < 4; ++ks){
      s0 = MFMA32(kf[ks], Qh0[ks], s0);
      s1 = MFMA32(kf[ks], Qh1[ks], s1);
    }
    #pragma unroll
    for (int e = 0; e < 16; e += 4){
      pa0 += exp2f(s0[e+0]); pa1 += exp2f(s0[e+1]);
      pa2 += exp2f(s0[e+2]); pa3 += exp2f(s0[e+3]);
      pb0 += exp2f(s1[e+0]); pb1 += exp2f(s1[e+1]);
      pb2 += exp2f(s1[e+2]); pb3 += exp2f(s1[e+3]);
    }
  }
  float l0 = (pa0+pa1) + (pa2+pa3);
  float l1 = (pb0+pb1) + (pb2+pb3);
  l0 += __shfl_xor(l0, 32);
  l1 += __shfl_xor(l1, 32);
  if (lane < 32){
    ldsL[0][w*32 + col] = l0;
    ldsL[1][w*32 + col] = l1;
  }
  __syncthreads();
  if (tid < 64){
    int tt = tid >> 5, q = tid & 31;
    float lt = (ldsL[tt][q] + ldsL[tt][32+q]) + (ldsL[tt][64+q] + ldsL[tt][96+q]);
    rlbuf[(size_t)bh*2048 + qt2*64 + tt*32 + q] = 1.0f / lt;
  }
}

// ---------------- attn phase 2: weights + PV (R16-exact) ----------------
__global__ __launch_bounds__(256,3) void attn_pv(
    const __hip_bfloat16* __restrict__ qh, const __hip_bfloat16* __restrict__ ql,
    const __hip_bfloat16* __restrict__ kh,
    const __hip_bfloat16* __restrict__ vT,
    const float* __restrict__ rlbuf,
    float* __restrict__ wout,
    __hip_bfloat16* __restrict__ attnh, __hip_bfloat16* __restrict__ attnl)
{
  __shared__ __align__(16) float ldsX[4*32*36];   // 18 KB: per-wave W scratch / PV merge
  __shared__ float ldsRL[32];

  const int tid  = threadIdx.x;
  const int w    = tid >> 6;
  const int lane = tid & 63;
  const int col  = lane & 31;
  const int hi   = lane >> 5;
  const int bh = blockIdx.x % 24, qt = blockIdx.x / 24;

  const __hip_bfloat16* qr_h = qh + ((size_t)bh*2048 + qt*32 + col)*64 + hi*8;
  const __hip_bfloat16* qr_l = ql + ((size_t)bh*2048 + qt*32 + col)*64 + hi*8;
  s16x8 Qh[4], Ql[4];
  #pragma unroll
  for (int ks = 0; ks < 4; ++ks){
    Qh[ks] = *(const s16x8*)(qr_h + ks*16);
    Ql[ks] = *(const s16x8*)(qr_l + ks*16);
  }

  if (tid < 32) ldsRL[tid] = rlbuf[(size_t)bh*2048 + qt*32 + tid];
  __syncthreads();
  const float rl = ldsRL[col];

  const __hip_bfloat16* kb = kh + (size_t)bh*2048*64;     // [key][64]
  const __hip_bfloat16* vb = vT + (size_t)bh*64*2048;     // [d][key]
  float* W = ldsX + w*1152;                               // 32 x 36 floats

  s16x8 kfn[4];
  {
    const __hip_bfloat16* kr = kb + ((size_t)(w*16)*32 + col)*64 + hi*8;
    #pragma unroll
    for (int ks = 0; ks < 4; ++ks) kfn[ks] = *(const s16x8*)(kr + ks*16);
  }

  f32x16 pv0, pv1;
  #pragma unroll
  for (int e = 0; e < 16; ++e){ pv0[e]=0.f; pv1[e]=0.f; }
  float* wq = wout + ((size_t)bh*2048 + (size_t)qt*32)*2048;

  for (int c = 0; c < 16; ++c){
    const int key0 = (w*16 + c)*32;
    s16x8 kf[4];
    #pragma unroll
    for (int ks = 0; ks < 4; ++ks) kf[ks] = kfn[ks];
    if (c < 15){
      const __hip_bfloat16* kr = kb + ((size_t)(w*16 + c + 1)*32 + col)*64 + hi*8;
      #pragma unroll
      for (int ks = 0; ks < 4; ++ks) kfn[ks] = *(const s16x8*)(kr + ks*16);
    }
    s16x8 vv[2][2];
    #pragma unroll
    for (int ww = 0; ww < 2; ++ww)
      #pragma unroll
      for (int dt = 0; dt < 2; ++dt)
        vv[ww][dt] = *(const s16x8*)(vb + ((size_t)(dt*32+col)*2048 + key0 + ww*16 + hi*8));

    f32x16 s0;
    #pragma unroll
    for (int e = 0; e < 16; ++e) s0[e] = 0.f;
    #pragma unroll
    for (int ks = 0; ks < 4; ++ks){
      s0 = MFMA32(kf[ks], Qh[ks], s0);
      s0 = MFMA32(kf[ks], Ql[ks], s0);
    }
    #pragma unroll
    for (int e = 0; e < 16; ++e) s0[e] = exp2f(s0[e]);   // unnormalized p, q-row = col

    // ---- normalized weights -> LDS (transpose) -> coalesced global ----
    #pragma unroll
    for (int rq = 0; rq < 4; ++rq){
      f32x4 f;
      f[0]=s0[rq*4+0]*rl; f[1]=s0[rq*4+1]*rl; f[2]=s0[rq*4+2]*rl; f[3]=s0[rq*4+3]*rl;
      *(f32x4*)(W + col*36 + rq*8 + hi*4) = f;           // key idx rq*8+hi*4+j
    }
    #pragma unroll
    for (int it = 0; it < 4; ++it){
      int q  = it*8 + (lane>>3);
      int k4 = (lane&7)*4;
      f32x4 f = *(const f32x4*)(W + q*36 + k4);
      *(f32x4*)(wq + (size_t)q*2048 + key0 + k4) = f;    // 8 rows x 128B per instr
    }

    // ---- pack p -> bf16 A-frags, PV ----
    #pragma unroll
    for (int ww = 0; ww < 2; ++ww){
      const int e0 = ww*8;
      unsigned wa = pack2(s0[e0+0], s0[e0+1]);
      unsigned wb = pack2(s0[e0+2], s0[e0+3]);
      unsigned wc = pack2(s0[e0+4], s0[e0+5]);
      unsigned wd = pack2(s0[e0+6], s0[e0+7]);
      plane32swap(wa, wc);
      plane32swap(wb, wd);
      union { unsigned u[4]; s16x8 v; } cv;
      cv.u[0]=wa; cv.u[1]=wb; cv.u[2]=wc; cv.u[3]=wd;
      pv0 = MFMA32(cv.v, vv[ww][0], pv0);
      pv1 = MFMA32(cv.v, vv[ww][1], pv1);
    }
  }

  __syncthreads();   // ldsX transitions from W-scratch to PV-merge buffer

  float* ldsPV = ldsX;
  if (w >= 2){
    const int buf = w - 2;
    #pragma unroll
    for (int e = 0; e < 16; ++e){
      ldsPV[(e)   *128 + buf*64 + lane] = pv0[e];
      ldsPV[(16+e)*128 + buf*64 + lane] = pv1[e];
    }
  }
  __syncthreads();
  if (w < 2){
    #pragma unroll
    for (int e = 0; e < 16; ++e){
      pv0[e] += ldsPV[(e)   *128 + w*64 + lane];
      pv1[e] += ldsPV[(16+e)*128 + w*64 + lane];
    }
  }
  __syncthreads();
  if (w == 1){
    #pragma unroll
    for (int e = 0; e < 16; ++e){
      ldsPV[(e)   *128 + lane] = pv0[e];
      ldsPV[(16+e)*128 + lane] = pv1[e];
    }
  }
  __syncthreads();
  if (w == 0){
    #pragma unroll
    for (int e = 0; e < 16; ++e){
      pv0[e] += ldsPV[(e)   *128 + lane];
      pv1[e] += ldsPV[(16+e)*128 + lane];
    }
    const int b_ = bh / 12, hh = bh % 12;
    #pragma unroll
    for (int e = 0; e < 16; ++e){
      int qsub = (e&3) + 8*(e>>2) + 4*hi;        // q-row of THIS register (PV D-layout)
      float re = ldsRL[qsub];
      int qrow = qt*32 + qsub;
      size_t base = ((size_t)b_*2048 + qrow)*768 + hh*64;
      __hip_bfloat16 h0, l0, h1, l1;
      split2(pv0[e]*re, h0, l0);
      split2(pv1[e]*re, h1, l1);
      attnh[base + col]      = h0; attnl[base + col]      = l0;
      attnh[base + 32 + col] = h1; attnl[base + 32 + col] = l1;
    }
  }
}

// ---------------- launch ----------------
extern "C" void kernel_launch(void* const* d_in, const int* in_sizes, int n_in,
                              void* d_out, int out_size, void* d_ws, size_t ws_size,
                              hipStream_t stream){
  const float* Q  = (const float*)d_in[0];
  const float* Kx = (const float*)d_in[1];
  const float* V  = (const float*)d_in[2];
  const float* Wq = (const float*)d_in[3];
  const float* bq = (const float*)d_in[4];
  const float* Wk = (const float*)d_in[5];
  const float* bk = (const float*)d_in[6];
  const float* Wv = (const float*)d_in[7];
  const float* bv = (const float*)d_in[8];
  const float* Wo = (const float*)d_in[9];
  const float* bo = (const float*)d_in[10];

  float* out = (float*)d_out;
  float* wts = out + (size_t)2*2048*768;

  char* cur = (char*)d_ws;
  auto alloc = [&](size_t elems)->__hip_bfloat16*{
    __hip_bfloat16* p = (__hip_bfloat16*)cur;
    cur += ((elems*2 + 255) & ~(size_t)255);
    return p;
  };
  const size_t NE = (size_t)4096*768;
  const size_t WE = (size_t)768*768;

  __hip_bfloat16 *QIh=alloc(NE), *KIh=alloc(NE), *VIh=alloc(NE);
  __hip_bfloat16 *Wqh=alloc(WE), *Wkh=alloc(WE), *Wvh=alloc(WE),
                 *Woh=alloc(WE), *Wol=alloc(WE);
  __hip_bfloat16 *qhp=alloc(NE), *qlp=alloc(NE), *khp=alloc(NE),
                 *vTp=alloc(NE);
  __hip_bfloat16 *ath=alloc(NE), *atl=alloc(NE);
  float* rlbuf = (float*)alloc(2*24*2048);   // 49152 floats

  split_all<<<11520, 256, 0, stream>>>(Q, Kx, V, Wq, Wk, Wv, Wo,
      QIh, KIh, VIh, Wqh, Wkh, Wvh, Woh, Wol);

  // log2-domain softmax: bake log2(e)/8 into the Q projection scale
  gemm_qkv<<<1152, 256, 0, stream>>>(
      QIh, KIh, VIh,
      Wqh, Wkh, Wvh,
      bq, bk, bv, 0.18033688011112042f,
      qhp, qlp, khp, vTp);

  attn_l <<<768,  256, 0, stream>>>(qhp, khp, rlbuf);
  attn_pv<<<1536, 256, 0, stream>>>(qhp, qlp, khp, vTp, rlbuf, wts, ath, atl);

  gemm_o<<<768, 256, 0, stream>>>(ath,atl,Woh,Wol,bo, out);
}

// Round 19
// 235.421 us; speedup vs baseline: 1.4073x; 1.0209x over previous
//
#include <hip/hip_runtime.h>
#include <hip/hip_bf16.h>

typedef __attribute__((ext_vector_type(4)))  float f32x4;
typedef __attribute__((ext_vector_type(16))) float f32x16;
typedef __attribute__((ext_vector_type(8)))  short s16x8;

#define MFMA(a,b,c)   __builtin_amdgcn_mfma_f32_16x16x32_bf16(a,b,c,0,0,0)
#define MFMA32(a,b,c) __builtin_amdgcn_mfma_f32_32x32x16_bf16(a,b,c,0,0,0)

__device__ __forceinline__ void gll16(const void* gptr, void* lptr){
  auto g = (const __attribute__((address_space(1))) unsigned int*)gptr;
  auto l = (__attribute__((address_space(3))) unsigned int*)lptr;
  __builtin_amdgcn_global_load_lds(g, l, 16, 0, 0);
}

__device__ __forceinline__ void split2(float x, __hip_bfloat16& h, __hip_bfloat16& l){
  h = __float2bfloat16(x);
  l = __float2bfloat16(x - __bfloat162float(h));
}

__device__ __forceinline__ unsigned short bf16bits(float x){
  __hip_bfloat16 h = __float2bfloat16(x);
  return *reinterpret_cast<unsigned short*>(&h);
}
__device__ __forceinline__ unsigned pack2(float lo, float hi){
  return (unsigned)bf16bits(lo) | ((unsigned)bf16bits(hi) << 16);
}
__device__ __forceinline__ void plane32swap(unsigned &a, unsigned &b){
  asm volatile("v_permlane32_swap_b32 %0, %1" : "+v"(a), "+v"(b));
}

// ---------------- fused input split: fp32 -> bf16 (hi; lo only for Wo) ----------------
__global__ __launch_bounds__(256) void split_all(
  const float* __restrict__ Q, const float* __restrict__ K, const float* __restrict__ V,
  const float* __restrict__ Wq, const float* __restrict__ Wk,
  const float* __restrict__ Wv, const float* __restrict__ Wo,
  __hip_bfloat16* __restrict__ QIh,
  __hip_bfloat16* __restrict__ KIh,
  __hip_bfloat16* __restrict__ VIh,
  __hip_bfloat16* __restrict__ Wqh,
  __hip_bfloat16* __restrict__ Wkh,
  __hip_bfloat16* __restrict__ Wvh,
  __hip_bfloat16* __restrict__ Woh, __hip_bfloat16* __restrict__ Wol)
{
  const int NE4 = 786432, WE4 = 147456;
  int i = blockIdx.x*256 + threadIdx.x;
  const float* src; __hip_bfloat16 *dh, *dl = nullptr; int off;
  if (i < 3*NE4){
    int seg = i / NE4; off = i - seg*NE4;
    src = seg==0 ? Q   : (seg==1 ? K   : V);
    dh  = seg==0 ? QIh : (seg==1 ? KIh : VIh);
  } else {
    int j = i - 3*NE4; int seg = j / WE4; off = j - seg*WE4;
    src = seg==0 ? Wq  : (seg==1 ? Wk  : (seg==2 ? Wv  : Wo));
    dh  = seg==0 ? Wqh : (seg==1 ? Wkh : (seg==2 ? Wvh : Woh));
    if (seg == 3) dl = Wol;
  }
  float4 x = ((const float4*)src)[off];
  __hip_bfloat16 h0,l0,h1,l1,h2,l2,h3,l3;
  split2(x.x,h0,l0); split2(x.y,h1,l1); split2(x.z,h2,l2); split2(x.w,h3,l3);
  union { __hip_bfloat16 b[4]; ushort4 u; } H, L;
  H.b[0]=h0; H.b[1]=h1; H.b[2]=h2; H.b[3]=h3;
  L.b[0]=l0; L.b[1]=l1; L.b[2]=l2; L.b[3]=l3;
  *(ushort4*)(dh + (size_t)off*4) = H.u;
  if (dl) *(ushort4*)(dl + (size_t)off*4) = L.u;
}

// ---------------- fused QKV GEMM: 1-term, 2-phase dbuf, BM=64 x BN=128 ----------------
// All projections 1-term, all outputs plain bf16 (q is consumed by 1-term attn QK now:
// attn_pv logits are bit-identical to attn_l's -> exact normalization).
__global__ __launch_bounds__(256) void gemm_qkv(
    const __hip_bfloat16* __restrict__ QAh,
    const __hip_bfloat16* __restrict__ KAh,
    const __hip_bfloat16* __restrict__ VAh,
    const __hip_bfloat16* __restrict__ WqH,
    const __hip_bfloat16* __restrict__ WkH,
    const __hip_bfloat16* __restrict__ WvH,
    const float* __restrict__ bq, const float* __restrict__ bk, const float* __restrict__ bv,
    float qscale,
    __hip_bfloat16* __restrict__ qhp,
    __hip_bfloat16* __restrict__ khp, __hip_bfloat16* __restrict__ vTp)
{
  __shared__ __align__(16) __hip_bfloat16 lds[24576];   // 48 KB: 2 bufs x (A 8KB + B 16KB)

  const int tid = threadIdx.x;
  const int w = tid >> 6, lane = tid & 63, r = lane & 15, g = lane >> 4;
  const int wg = blockIdx.x;
  const int seg = wg / 384;
  const int t = wg % 384;
  const int tm = t / 6, tn = t % 6;

  const __hip_bfloat16* Ah = seg==0 ? QAh : (seg==1 ? KAh : VAh);
  const __hip_bfloat16* Bh = seg==0 ? WqH : (seg==1 ? WkH : WvH);
  const float* bias        = seg==0 ? bq  : (seg==1 ? bk  : bv);

  const char* gA_h = (const char*)Ah + (size_t)tm*64*768*2;
  const char* gB_h = (const char*)Bh + (size_t)tn*128*768*2;

  f32x4 acc[8] = {};

  auto stage = [&](int buf, int kbe){
    #pragma unroll
    for (int i = 0; i < 2; ++i){   // A: 64 rows x 128 B
      int lb = i*4096 + tid*16;
      int row = lb >> 7, colb = lb & 127;
      gll16(gA_h + (size_t)row*1536 + kbe*2 + colb, (char*)lds + buf*24576 + i*4096 + w*1024);
    }
    #pragma unroll
    for (int i = 0; i < 4; ++i){   // B: 128 rows x 128 B
      int lb = i*4096 + tid*16;
      int row = lb >> 7, colb = lb & 127;
      gll16(gB_h + (size_t)row*1536 + kbe*2 + colb, (char*)lds + buf*24576 + 8192 + i*4096 + w*1024);
    }
  };
  int cur = 0;
  stage(0, 0);
  __syncthreads();
  for (int it = 0; it < 12; ++it){
    if (it + 1 < 12) stage(cur ^ 1, (it+1)*64);
    const __hip_bfloat16* A = lds + cur*12288;
    const __hip_bfloat16* B = lds + cur*12288 + 4096;
    #pragma unroll
    for (int c = 0; c < 2; ++c){
      int aoff = (w*16 + r)*64 + c*32 + g*8;
      s16x8 a_h = *(const s16x8*)(A + aoff);
      #pragma unroll
      for (int j = 0; j < 8; ++j){
        s16x8 b_h = *(const s16x8*)(B + (j*16 + r)*64 + c*32 + g*8);
        acc[j] = MFMA(a_h, b_h, acc[j]);
      }
    }
    __syncthreads();
    cur ^= 1;
  }

  #pragma unroll
  for (int j = 0; j < 8; ++j){
    #pragma unroll
    for (int e = 0; e < 4; ++e){
      int m = tm*64 + w*16 + g*4 + e;   // row in [4096]
      int n = tn*128 + j*16 + r;        // out feature in [768]
      float v = acc[j][e] + bias[n];
      int b = m >> 11, s = m & 2047;
      if (seg == 0){
        size_t idx = ((size_t)(b*12 + (n>>6))*2048 + s)*64 + (n & 63);
        qhp[idx] = __float2bfloat16(v*qscale);
      } else if (seg == 1){
        size_t idx = ((size_t)(b*12 + (n>>6))*2048 + s)*64 + (n & 63);
        khp[idx] = __float2bfloat16(v);
      } else {
        size_t idx = ((size_t)(b*12 + (n>>6))*64 + (n & 63))*2048 + s;
        vTp[idx] = __float2bfloat16(v);
      }
    }
  }
}

// ---------------- out-proj GEMM: attn[4096x768] x Wo[768x768]^T + bo -> fp32 (3-term) ----------------
__global__ __launch_bounds__(256) void gemm_o(
    const __hip_bfloat16* __restrict__ Ah, const __hip_bfloat16* __restrict__ Al,
    const __hip_bfloat16* __restrict__ Bh, const __hip_bfloat16* __restrict__ Bl,
    const float* __restrict__ bias, float* __restrict__ o_f)
{
  __shared__ __align__(16) __hip_bfloat16 sAh[64*64];
  __shared__ __align__(16) __hip_bfloat16 sAl[64*64];
  __shared__ __align__(16) __hip_bfloat16 sBh[64*64];
  __shared__ __align__(16) __hip_bfloat16 sBl[64*64];

  const int tid = threadIdx.x;
  const int w = tid >> 6, lane = tid & 63, r = lane & 15, g = lane >> 4;
  const int t = blockIdx.x;
  const int tm = t / 12, tn = t % 12;

  const char* gA_h = (const char*)Ah + (size_t)tm*64*768*2;
  const char* gA_l = (const char*)Al + (size_t)tm*64*768*2;
  const char* gB_h = (const char*)Bh + (size_t)tn*64*768*2;
  const char* gB_l = (const char*)Bl + (size_t)tn*64*768*2;

  f32x4 acc[4] = {};

  for (int kb = 0; kb < 768; kb += 64){
    __syncthreads();
    #pragma unroll
    for (int i = 0; i < 2; ++i){
      int lb = i*4096 + tid*16;
      int row = lb >> 7, colb = lb & 127;
      gll16(gA_h + (size_t)row*1536 + kb*2 + colb, (char*)sAh + i*4096 + w*1024);
      gll16(gA_l + (size_t)row*1536 + kb*2 + colb, (char*)sAl + i*4096 + w*1024);
      gll16(gB_h + (size_t)row*1536 + kb*2 + colb, (char*)sBh + i*4096 + w*1024);
      gll16(gB_l + (size_t)row*1536 + kb*2 + colb, (char*)sBl + i*4096 + w*1024);
    }
    __syncthreads();
    #pragma unroll
    for (int c = 0; c < 2; ++c){
      int aoff = (w*16 + r)*64 + c*32 + g*8;
      s16x8 a_h = *(const s16x8*)(sAh + aoff);
      s16x8 a_l = *(const s16x8*)(sAl + aoff);
      #pragma unroll
      for (int j = 0; j < 4; ++j){
        int boff = (j*16 + r)*64 + c*32 + g*8;
        s16x8 b_h = *(const s16x8*)(sBh + boff);
        s16x8 b_l = *(const s16x8*)(sBl + boff);
        acc[j] = MFMA(a_h, b_h, acc[j]);
        acc[j] = MFMA(a_l, b_h, acc[j]);
        acc[j] = MFMA(a_h, b_l, acc[j]);
      }
    }
  }

  #pragma unroll
  for (int j = 0; j < 4; ++j){
    #pragma unroll
    for (int e = 0; e < 4; ++e){
      int m = tm*64 + w*16 + g*4 + e;
      int n = tn*64 + j*16 + r;
      o_f[(size_t)m*768 + n] = acc[j][e] + bias[n];
    }
  }
}

// ---------------- attn phase 1: softmax denominators (R17-exact) ----------------
__global__ __launch_bounds__(256,3) void attn_l(
    const __hip_bfloat16* __restrict__ qh,
    const __hip_bfloat16* __restrict__ kh,
    float* __restrict__ rlbuf)
{
  __shared__ float ldsL[2][128];
  const int tid  = threadIdx.x;
  const int w    = tid >> 6;
  const int lane = tid & 63;
  const int col  = lane & 31;
  const int hi   = lane >> 5;
  const int bh = blockIdx.x % 24, qt2 = blockIdx.x / 24;

  const __hip_bfloat16* qr0 = qh + ((size_t)bh*2048 + qt2*64 + col)*64 + hi*8;
  const __hip_bfloat16* qr1 = qr0 + 32*64;
  s16x8 Qh0[4], Qh1[4];
  #pragma unroll
  for (int ks = 0; ks < 4; ++ks){
    Qh0[ks] = *(const s16x8*)(qr0 + ks*16);
    Qh1[ks] = *(const s16x8*)(qr1 + ks*16);
  }

  const __hip_bfloat16* kb = kh + (size_t)bh*2048*64;

  s16x8 kfn[4];
  {
    const __hip_bfloat16* kr = kb + ((size_t)(w*16)*32 + col)*64 + hi*8;
    #pragma unroll
    for (int ks = 0; ks < 4; ++ks) kfn[ks] = *(const s16x8*)(kr + ks*16);
  }

  float pa0=0.f, pa1=0.f, pa2=0.f, pa3=0.f;
  float pb0=0.f, pb1=0.f, pb2=0.f, pb3=0.f;
  for (int c = 0; c < 16; ++c){
    s16x8 kf[4];
    #pragma unroll
    for (int ks = 0; ks < 4; ++ks) kf[ks] = kfn[ks];
    if (c < 15){
      const __hip_bfloat16* kr = kb + ((size_t)(w*16 + c + 1)*32 + col)*64 + hi*8;
      #pragma unroll
      for (int ks = 0; ks < 4; ++ks) kfn[ks] = *(const s16x8*)(kr + ks*16);
    }
    f32x16 s0, s1;
    #pragma unroll
    for (int e = 0; e < 16; ++e){ s0[e] = 0.f; s1[e] = 0.f; }
    #pragma unroll
    for (int ks = 0; ks < 4; ++ks){
      s0 = MFMA32(kf[ks], Qh0[ks], s0);
      s1 = MFMA32(kf[ks], Qh1[ks], s1);
    }
    #pragma unroll
    for (int e = 0; e < 16; e += 4){
      pa0 += exp2f(s0[e+0]); pa1 += exp2f(s0[e+1]);
      pa2 += exp2f(s0[e+2]); pa3 += exp2f(s0[e+3]);
      pb0 += exp2f(s1[e+0]); pb1 += exp2f(s1[e+1]);
      pb2 += exp2f(s1[e+2]); pb3 += exp2f(s1[e+3]);
    }
  }
  float l0 = (pa0+pa1) + (pa2+pa3);
  float l1 = (pb0+pb1) + (pb2+pb3);
  l0 += __shfl_xor(l0, 32);
  l1 += __shfl_xor(l1, 32);
  if (lane < 32){
    ldsL[0][w*32 + col] = l0;
    ldsL[1][w*32 + col] = l1;
  }
  __syncthreads();
  if (tid < 64){
    int tt = tid >> 5, q = tid & 31;
    float lt = (ldsL[tt][q] + ldsL[tt][32+q]) + (ldsL[tt][64+q] + ldsL[tt][96+q]);
    rlbuf[(size_t)bh*2048 + qt2*64 + tt*32 + q] = 1.0f / lt;
  }
}

// ---------------- attn phase 2: weights + PV, 1-term QK ----------------
// QK is now 1-term (bf16 q) -> logits BIT-IDENTICAL to attn_l's -> Σp == l exactly
// (normalization error vanishes). MFMA per chunk 12 -> 8; Ql registers freed.
__global__ __launch_bounds__(256,3) void attn_pv(
    const __hip_bfloat16* __restrict__ qh,
    const __hip_bfloat16* __restrict__ kh,
    const __hip_bfloat16* __restrict__ vT,
    const float* __restrict__ rlbuf,
    float* __restrict__ wout,
    __hip_bfloat16* __restrict__ attnh, __hip_bfloat16* __restrict__ attnl)
{
  __shared__ __align__(16) float ldsX[4*32*36];   // 18 KB: per-wave W scratch / PV merge
  __shared__ float ldsRL[32];

  const int tid  = threadIdx.x;
  const int w    = tid >> 6;
  const int lane = tid & 63;
  const int col  = lane & 31;
  const int hi   = lane >> 5;
  const int bh = blockIdx.x % 24, qt = blockIdx.x / 24;

  const __hip_bfloat16* qr_h = qh + ((size_t)bh*2048 + qt*32 + col)*64 + hi*8;
  s16x8 Qh[4];
  #pragma unroll
  for (int ks = 0; ks < 4; ++ks) Qh[ks] = *(const s16x8*)(qr_h + ks*16);

  if (tid < 32) ldsRL[tid] = rlbuf[(size_t)bh*2048 + qt*32 + tid];
  __syncthreads();
  const float rl = ldsRL[col];

  const __hip_bfloat16* kb = kh + (size_t)bh*2048*64;     // [key][64]
  const __hip_bfloat16* vb = vT + (size_t)bh*64*2048;     // [d][key]
  float* W = ldsX + w*1152;                               // 32 x 36 floats

  s16x8 kfn[4];
  {
    const __hip_bfloat16* kr = kb + ((size_t)(w*16)*32 + col)*64 + hi*8;
    #pragma unroll
    for (int ks = 0; ks < 4; ++ks) kfn[ks] = *(const s16x8*)(kr + ks*16);
  }

  f32x16 pv0, pv1;
  #pragma unroll
  for (int e = 0; e < 16; ++e){ pv0[e]=0.f; pv1[e]=0.f; }
  float* wq = wout + ((size_t)bh*2048 + (size_t)qt*32)*2048;

  for (int c = 0; c < 16; ++c){
    const int key0 = (w*16 + c)*32;
    s16x8 kf[4];
    #pragma unroll
    for (int ks = 0; ks < 4; ++ks) kf[ks] = kfn[ks];
    if (c < 15){
      const __hip_bfloat16* kr = kb + ((size_t)(w*16 + c + 1)*32 + col)*64 + hi*8;
      #pragma unroll
      for (int ks = 0; ks < 4; ++ks) kfn[ks] = *(const s16x8*)(kr + ks*16);
    }
    s16x8 vv[2][2];
    #pragma unroll
    for (int ww = 0; ww < 2; ++ww)
      #pragma unroll
      for (int dt = 0; dt < 2; ++dt)
        vv[ww][dt] = *(const s16x8*)(vb + ((size_t)(dt*32+col)*2048 + key0 + ww*16 + hi*8));

    f32x16 s0;
    #pragma unroll
    for (int e = 0; e < 16; ++e) s0[e] = 0.f;
    #pragma unroll
    for (int ks = 0; ks < 4; ++ks) s0 = MFMA32(kf[ks], Qh[ks], s0);   // == attn_l logits
    #pragma unroll
    for (int e = 0; e < 16; ++e) s0[e] = exp2f(s0[e]);   // unnormalized p, q-row = col

    // ---- normalized weights -> LDS (transpose) -> coalesced global ----
    #pragma unroll
    for (int rq = 0; rq < 4; ++rq){
      f32x4 f;
      f[0]=s0[rq*4+0]*rl; f[1]=s0[rq*4+1]*rl; f[2]=s0[rq*4+2]*rl; f[3]=s0[rq*4+3]*rl;
      *(f32x4*)(W + col*36 + rq*8 + hi*4) = f;           // key idx rq*8+hi*4+j
    }
    #pragma unroll
    for (int it = 0; it < 4; ++it){
      int q  = it*8 + (lane>>3);
      int k4 = (lane&7)*4;
      f32x4 f = *(const f32x4*)(W + q*36 + k4);
      *(f32x4*)(wq + (size_t)q*2048 + key0 + k4) = f;    // 8 rows x 128B per instr
    }

    // ---- pack p -> bf16 A-frags, PV ----
    #pragma unroll
    for (int ww = 0; ww < 2; ++ww){
      const int e0 = ww*8;
      unsigned wa = pack2(s0[e0+0], s0[e0+1]);
      unsigned wb = pack2(s0[e0+2], s0[e0+3]);
      unsigned wc = pack2(s0[e0+4], s0[e0+5]);
      unsigned wd = pack2(s0[e0+6], s0[e0+7]);
      plane32swap(wa, wc);
      plane32swap(wb, wd);
      union { unsigned u[4]; s16x8 v; } cv;
      cv.u[0]=wa; cv.u[1]=wb; cv.u[2]=wc; cv.u[3]=wd;
      pv0 = MFMA32(cv.v, vv[ww][0], pv0);
      pv1 = MFMA32(cv.v, vv[ww][1], pv1);
    }
  }

  __syncthreads();   // ldsX transitions from W-scratch to PV-merge buffer

  float* ldsPV = ldsX;
  if (w >= 2){
    const int buf = w - 2;
    #pragma unroll
    for (int e = 0; e < 16; ++e){
      ldsPV[(e)   *128 + buf*64 + lane] = pv0[e];
      ldsPV[(16+e)*128 + buf*64 + lane] = pv1[e];
    }
  }
  __syncthreads();
  if (w < 2){
    #pragma unroll
    for (int e = 0; e < 16; ++e){
      pv0[e] += ldsPV[(e)   *128 + w*64 + lane];
      pv1[e] += ldsPV[(16+e)*128 + w*64 + lane];
    }
  }
  __syncthreads();
  if (w == 1){
    #pragma unroll
    for (int e = 0; e < 16; ++e){
      ldsPV[(e)   *128 + lane] = pv0[e];
      ldsPV[(16+e)*128 + lane] = pv1[e];
    }
  }
  __syncthreads();
  if (w == 0){
    #pragma unroll
    for (int e = 0; e < 16; ++e){
      pv0[e] += ldsPV[(e)   *128 + lane];
      pv1[e] += ldsPV[(16+e)*128 + lane];
    }
    const int b_ = bh / 12, hh = bh % 12;
    #pragma unroll
    for (int e = 0; e < 16; ++e){
      int qsub = (e&3) + 8*(e>>2) + 4*hi;        // q-row of THIS register (PV D-layout)
      float re = ldsRL[qsub];
      int qrow = qt*32 + qsub;
      size_t base = ((size_t)b_*2048 + qrow)*768 + hh*64;
      __hip_bfloat16 h0, l0, h1, l1;
      split2(pv0[e]*re, h0, l0);
      split2(pv1[e]*re, h1, l1);
      attnh[base + col]      = h0; attnl[base + col]      = l0;
      attnh[base + 32 + col] = h1; attnl[base + 32 + col] = l1;
    }
  }
}

// ---------------- launch ----------------
extern "C" void kernel_launch(void* const* d_in, const int* in_sizes, int n_in,
                              void* d_out, int out_size, void* d_ws, size_t ws_size,
                              hipStream_t stream){
  const float* Q  = (const float*)d_in[0];
  const float* Kx = (const float*)d_in[1];
  const float* V  = (const float*)d_in[2];
  const float* Wq = (const float*)d_in[3];
  const float* bq = (const float*)d_in[4];
  const float* Wk = (const float*)d_in[5];
  const float* bk = (const float*)d_in[6];
  const float* Wv = (const float*)d_in[7];
  const float* bv = (const float*)d_in[8];
  const float* Wo = (const float*)d_in[9];
  const float* bo = (const float*)d_in[10];

  float* out = (float*)d_out;
  float* wts = out + (size_t)2*2048*768;

  char* cur = (char*)d_ws;
  auto alloc = [&](size_t elems)->__hip_bfloat16*{
    __hip_bfloat16* p = (__hip_bfloat16*)cur;
    cur += ((elems*2 + 255) & ~(size_t)255);
    return p;
  };
  const size_t NE = (size_t)4096*768;
  const size_t WE = (size_t)768*768;

  __hip_bfloat16 *QIh=alloc(NE), *KIh=alloc(NE), *VIh=alloc(NE);
  __hip_bfloat16 *Wqh=alloc(WE), *Wkh=alloc(WE), *Wvh=alloc(WE),
                 *Woh=alloc(WE), *Wol=alloc(WE);
  __hip_bfloat16 *qhp=alloc(NE), *khp=alloc(NE), *vTp=alloc(NE);
  __hip_bfloat16 *ath=alloc(NE), *atl=alloc(NE);
  float* rlbuf = (float*)alloc(2*24*2048);   // 49152 floats

  split_all<<<11520, 256, 0, stream>>>(Q, Kx, V, Wq, Wk, Wv, Wo,
      QIh, KIh, VIh, Wqh, Wkh, Wvh, Woh, Wol);

  // log2-domain softmax: bake log2(e)/8 into the Q projection scale
  gemm_qkv<<<1152, 256, 0, stream>>>(
      QIh, KIh, VIh,
      Wqh, Wkh, Wvh,
      bq, bk, bv, 0.18033688011112042f,
      qhp, khp, vTp);

  attn_l <<<768,  256, 0, stream>>>(qhp, khp, rlbuf);
  attn_pv<<<1536, 256, 0, stream>>>(qhp, khp, vTp, rlbuf, wts, ath, atl);

  gemm_o<<<768, 256, 0, stream>>>(ath,atl,Woh,Wol,bo, out);
}